// Round 17
// baseline (79.538 us; speedup 1.0000x reference)
//
#include <hip/hip_runtime.h>

typedef short bf16x8 __attribute__((ext_vector_type(8)));
typedef float f32x16 __attribute__((ext_vector_type(16)));

#define DI __device__ __forceinline__

constexpr int BS = 2, CH = 128;
constexpr int NQ = 16384, NM = 4096;
constexpr size_t NX = (size_t)BS * CH * NQ;   // elements per output tensor

DI float bf2f(ushort u) { unsigned v = ((unsigned)u) << 16; return __builtin_bit_cast(float, v); }
DI ushort f2bf(float f) {
  unsigned u = __builtin_bit_cast(unsigned, f);
  u += 0x7FFFu + ((u >> 16) & 1u);   // RNE
  return (ushort)(u >> 16);
}
DI float ldany(const void* p, size_t i, int f) {
  return f ? ((const float*)p)[i] : bf2f(((const ushort*)p)[i]);
}
DI f32x16 mfma_bf16(bf16x8 a, bf16x8 b, f32x16 c) {
  return __builtin_amdgcn_mfma_f32_32x32x16_bf16(a, b, c, 0, 0, 0);
}
DI float fexp2(float x) { return __builtin_amdgcn_exp2f(x); }   // 1x v_exp_f32

// block-local parallel dtype sniff (first 256 ushorts of x); all blocks agree.
DI int sniff_block(const void* x, int t, int* cnt_sh) {
  const ushort* u = (const ushort*)x;
  if (t == 0) { cnt_sh[0] = 0; cnt_sh[1] = 0; }
  __syncthreads();
  if (t < 256) {
    float v = bf2f(u[t]);
    if (!(fabsf(v) < 1e9f)) atomicAdd(&cnt_sh[0], 1);
    if (((t & 1) == 0) && (u[t] == 0)) atomicAdd(&cnt_sh[1], 1);
  }
  __syncthreads();
  return (cnt_sh[0] >= 8 || cnt_sh[1] >= 100) ? 1 : 0;   // 1 = f32 buffers
}

// ---------------- projections via MFMA (self-contained: builds wBf in LDS) ----
// 256 threads = 4 waves = (qhalf) x (khalf); 64 q per block.
__global__ __launch_bounds__(256) void k_proj(
    const void* __restrict__ x,
    const void* __restrict__ wT, const void* __restrict__ bT,
    const void* __restrict__ wP, const void* __restrict__ bP,
    const void* __restrict__ wG, const void* __restrict__ bG,
    ushort* __restrict__ theta, ushort* __restrict__ phi, ushort* __restrict__ gm)
{
  int b = blockIdx.y;
  int qt = blockIdx.x;              // 0..255, 64 q each
  int t = threadIdx.x;
  int w = t >> 6, l = t & 63, lr = l & 31, lh = l >> 5;
  int qhalf = w & 1, khalf = w >> 1;

  __shared__ int cnt_sh[2];
  __shared__ __align__(16) uint4 wBf_sh[24][64];   // 24 KB
  __shared__ float bias_sh[96];
  __shared__ float tile[64][33];

  int f = sniff_block(x, t, cnt_sh);

  for (int idx = t; idx < 1536; idx += 256) {
    int kb = idx / 192, rem = idx % 192;
    int ob = rem >> 6, lane = rem & 63;
    int r = ob * 32 + (lane & 31);
    int c = kb * 16 + (lane >> 5) * 8;
    const void* src; int row;
    if (r < 16)      { src = wT; row = r; }
    else if (r < 32) { src = wP; row = r - 16; }
    else             { src = wG; row = r - 32; }
    union { uint4 v4; ushort s[8]; } o;
    #pragma unroll
    for (int j = 0; j < 8; ++j) o.s[j] = f2bf(ldany(src, (size_t)row * 128 + c + j, f));
    wBf_sh[kb * 3 + ob][lane] = o.v4;
  }
  if (t < 16)       bias_sh[t] = ldany(bT, t, f);
  else if (t < 32)  bias_sh[t] = ldany(bP, t - 16, f);
  else if (t < 96)  bias_sh[t] = ldany(bG, t - 32, f);
  __syncthreads();

  size_t xbase = (size_t)b * CH * NQ + qt * 64 + qhalf * 32 + lr;

  f32x16 acc0, acc1, acc2;
  #pragma unroll
  for (int i = 0; i < 16; ++i) { acc0[i] = 0.f; acc1[i] = 0.f; acc2[i] = 0.f; }

  #pragma unroll
  for (int kk = 0; kk < 4; ++kk) {
    int kb = khalf * 4 + kk;
    union { uint4 v4; ushort s[8]; } a;
    int cb = kb * 16 + lh * 8;
    if (f) {
      const float* xf = (const float*)x;
      #pragma unroll
      for (int j = 0; j < 8; ++j) a.s[j] = f2bf(xf[xbase + (size_t)(cb + j) * NQ]);
    } else {
      const ushort* xu = (const ushort*)x;
      #pragma unroll
      for (int j = 0; j < 8; ++j) a.s[j] = xu[xbase + (size_t)(cb + j) * NQ];
    }
    bf16x8 aF = __builtin_bit_cast(bf16x8, a.v4);
    uint4 b0 = wBf_sh[kb * 3 + 0][l];
    uint4 b1 = wBf_sh[kb * 3 + 1][l];
    uint4 b2 = wBf_sh[kb * 3 + 2][l];
    acc0 = mfma_bf16(aF, __builtin_bit_cast(bf16x8, b0), acc0);
    acc1 = mfma_bf16(aF, __builtin_bit_cast(bf16x8, b1), acc1);
    acc2 = mfma_bf16(aF, __builtin_bit_cast(bf16x8, b2), acc2);
  }

  constexpr float L2E = 1.4426950408889634f;

  #pragma unroll
  for (int ob = 0; ob < 3; ++ob) {
    f32x16 A = (ob == 0) ? acc0 : ((ob == 1) ? acc1 : acc2);
    __syncthreads();
    if (khalf == 1) {
      #pragma unroll
      for (int r = 0; r < 16; ++r) {
        int qq = (r & 3) + 8 * (r >> 2) + 4 * lh;
        tile[qhalf * 32 + qq][lr] = A[r];
      }
    }
    __syncthreads();
    if (khalf == 0) {
      #pragma unroll
      for (int r = 0; r < 16; ++r) {
        int qq = (r & 3) + 8 * (r >> 2) + 4 * lh;
        tile[qhalf * 32 + qq][lr] += A[r];
      }
    }
    __syncthreads();
    if (ob == 0) {
      if (t < 64) {                      // theta
        union { uint4 v4[2]; ushort s[16]; } th;
        #pragma unroll
        for (int c = 0; c < 16; ++c)
          th.s[c] = f2bf(tanhf(tile[t][c] + bias_sh[c]) * L2E);
        uint4* dst = (uint4*)(theta + ((size_t)b * NQ + qt * 64 + t) * 16);
        dst[0] = th.v4[0]; dst[1] = th.v4[1];
      } else if (t < 128) {              // phi
        int idx = t - 64;
        int m = idx >> 2, c4 = (idx & 3) * 4;
        int h2 = m * 2;
        union { uint2 v2; ushort s[4]; } ph;
        #pragma unroll
        for (int cc = 0; cc < 4; ++cc) {
          int c = 16 + c4 + cc;
          float z = fmaxf(fmaxf(tile[h2][c], tile[h2 + 1][c]),
                          fmaxf(tile[32 + h2][c], tile[32 + h2 + 1][c]));
          ph.s[cc] = f2bf(tanhf(z + bias_sh[c]));
        }
        *(uint2*)(phi + ((size_t)b * NM + qt * 16 + m) * 16 + c4) = ph.v2;
      }
    } else {                             // g
      if (t < 128) {
        int cb = (ob - 1) * 32;
        int m = t >> 3, c4 = (t & 7) * 4;
        int h2 = m * 2;
        union { uint2 v2; ushort s[4]; } gv;
        #pragma unroll
        for (int cc = 0; cc < 4; ++cc) {
          int c = c4 + cc;
          float z = fmaxf(fmaxf(tile[h2][c], tile[h2 + 1][c]),
                          fmaxf(tile[32 + h2][c], tile[32 + h2 + 1][c]));
          gv.s[cc] = f2bf(z + bias_sh[32 + cb + c]);
        }
        *(uint2*)(gm + ((size_t)b * NM + qt * 16 + m) * 64 + cb + c4) = gv.v2;
      }
    }
  }
}

// ---------------- denominator + scale + PV B-frag pack (unchanged, R13) -------
__global__ __launch_bounds__(1024, 2) void k_denom2(
    const ushort* __restrict__ theta, const ushort* __restrict__ phi,
    const ushort* __restrict__ gm, uint4* __restrict__ gsF)
{
  int b = blockIdx.y, mb = blockIdx.x;   // 128 chunks of 32 m
  int t = threadIdx.x;
  int w = t >> 6, l = t & 63, lr = l & 31, lh = l >> 5;
  int mbase = mb * 32;

  __shared__ float part[16][33];
  __shared__ float dinv_sh[32];
  __shared__ float tile[32][65];

  bf16x8 pB = __builtin_bit_cast(bf16x8, *(const uint4*)(phi + ((size_t)b * NM + mbase + lr) * 16 + lh * 8));
  const ushort* thb = theta + ((size_t)b * NQ + w * 1024 + lr) * 16 + lh * 8;

  bf16x8 tA1 = __builtin_bit_cast(bf16x8, *(const uint4*)(thb + 512));
  f32x16 S;
  #pragma unroll
  for (int i = 0; i < 16; ++i) S[i] = 0.f;
  S = mfma_bf16(__builtin_bit_cast(bf16x8, *(const uint4*)thb), pB, S);

  float s = 0.f;
  for (int it = 0; it < 32; ++it) {
    bf16x8 tA2 = __builtin_bit_cast(bf16x8, *(const uint4*)(thb + (size_t)((it + 2) & 31) * 512));
    __builtin_amdgcn_sched_barrier(0);
    f32x16 Sn;
    #pragma unroll
    for (int i = 0; i < 16; ++i) Sn[i] = 0.f;
    Sn = mfma_bf16(tA1, pB, Sn);          // next tile's S overlaps this exp block
    #pragma unroll
    for (int r = 0; r < 16; ++r) s += fexp2(S[r]);
    S = Sn; tA1 = tA2;
  }
  s += __shfl_xor(s, 32, 64);
  if (l < 32) part[w][lr] = s;
  __syncthreads();

  if (t < 32) {
    float d = 0.f;
    #pragma unroll
    for (int p = 0; p < 16; ++p) d += part[p][t];
    dinv_sh[t] = 1.f / d;
  }
  __syncthreads();

  if (t < 256) {
    int m_loc = t >> 3, c = (t & 7) * 8;
    union { uint4 v4; ushort s[8]; } v;
    v.v4 = *(const uint4*)(gm + ((size_t)b * NM + mbase + m_loc) * 64 + c);
    float dv = dinv_sh[m_loc];
    #pragma unroll
    for (int j = 0; j < 8; ++j) tile[m_loc][c + j] = bf2f(v.s[j]) * dv;
  }
  __syncthreads();

  if (t < 256) {
    int ms_loc = t >> 7, ct = (t >> 6) & 1, lane = t & 63;
    int col = ct * 32 + (lane & 31);
    int rbase = ms_loc * 16 + (lane >> 5) * 8;
    union { uint4 v4; ushort s[8]; } o;
    #pragma unroll
    for (int j = 0; j < 8; ++j) o.s[j] = f2bf(tile[rbase + j][col]);
    int ms = (mbase >> 4) + ms_loc;
    gsF[(((size_t)b * 256 + ms) * 2 + ct) * 64 + lane] = o.v4;
  }
}

// ---------------- fused attention + output (R13 loop; self-contained wF;
//                  batch-aware XCD swizzle) ------------------------------------
// idx -> (xcd = idx&7, slot = idx>>3): b = xcd>>2, qt = (xcd&3)*64 + slot.
// All 512 blocks co-resident; each XCD serves ONE batch -> halves its L2 set.
__global__ __launch_bounds__(256, 3) void k_attn(
    const ushort* __restrict__ theta, const ushort* __restrict__ phi,
    const uint4* __restrict__ gsF, const void* __restrict__ wAG,
    const void* __restrict__ bAG, const void* __restrict__ x,
    const void* __restrict__ gamma, void* __restrict__ out_base)
{
  int idx = blockIdx.x;              // 0..511
  int xcd = idx & 7, slot = idx >> 3;
  int b = xcd >> 2;
  int q0 = ((xcd & 3) * 64 + slot) * 64;
  int t = threadIdx.x;
  int mq = t >> 6, l = t & 63, lr = l & 31, lh = l >> 5;

  __shared__ int cnt_sh[2];
  __shared__ __align__(16) uint4 wF_lds[16][64];   // 16 KB
  __shared__ float bag_sh[128];
  __shared__ float agPart[4][32][65];
  __shared__ __align__(16) ushort agF[32][80];

  int f = sniff_block(x, t, cnt_sh);

  for (int i = t; i < 1024; i += 256) {
    int lane = i & 63, ks = (i >> 6) & 3, ot = i >> 8;
    size_t src = (size_t)(ot * 32 + (lane & 31)) * 64 + ks * 16 + (lane >> 5) * 8;
    union { uint4 v4; ushort s[8]; } o;
    #pragma unroll
    for (int j = 0; j < 8; ++j) o.s[j] = f2bf(ldany(wAG, src + j, f));
    wF_lds[ot * 4 + ks][lane] = o.v4;
  }
  if (t < 128) bag_sh[t] = ldany(bAG, t, f);
  __syncthreads();

  bf16x8 tB0 = __builtin_bit_cast(bf16x8, *(const uint4*)(theta + ((size_t)b * NQ + q0 + lr) * 16 + lh * 8));
  bf16x8 tB1 = __builtin_bit_cast(bf16x8, *(const uint4*)(theta + ((size_t)b * NQ + q0 + 32 + lr) * 16 + lh * 8));

  const ushort* phb = phi + ((size_t)b * NM + lr) * 16 + lh * 8;
  const uint4* gF = gsF + (size_t)b * 32768;

  f32x16 a00, a01, a10, a11;
  #pragma unroll
  for (int i = 0; i < 16; ++i) { a00[i] = 0.f; a01[i] = 0.f; a10[i] = 0.f; a11[i] = 0.f; }
  f32x16 zero16;
  #pragma unroll
  for (int i = 0; i < 16; ++i) zero16[i] = 0.f;

  size_t gb0 = (size_t)(mq * 2) * 128;
  uint4 g00 = gF[gb0 + l];
  uint4 g01 = gF[gb0 + 64 + l];
  uint4 g10 = gF[gb0 + 128 + l];
  uint4 g11 = gF[gb0 + 192 + l];
  bf16x8 pA = __builtin_bit_cast(bf16x8, *(const uint4*)(phb + (size_t)(mq * 32) * 16));

  for (int it = 0; it < 32; ++it) {
    int it1 = (it + 1) & 31;
    size_t gb = (size_t)(mq * 2 + it1 * 8) * 128;
    uint4 n00 = gF[gb + l];
    uint4 n01 = gF[gb + 64 + l];
    uint4 n10 = gF[gb + 128 + l];
    uint4 n11 = gF[gb + 192 + l];
    bf16x8 pAn = __builtin_bit_cast(bf16x8, *(const uint4*)(phb + (size_t)(mq * 32 + it1 * 128) * 16));
    __builtin_amdgcn_sched_barrier(0);

    f32x16 Sa = mfma_bf16(pA, tB0, zero16);
    f32x16 Sb = mfma_bf16(pA, tB1, zero16);

    uint u0, u1, u2, u3, u4, u5, u6, u7;

    #pragma unroll
    for (int r = 0; r < 16; ++r) Sa[r] = fexp2(Sa[r]);
    asm("v_cvt_pk_bf16_f32 %0, %1, %2" : "=v"(u0) : "v"(Sa[0]),  "v"(Sa[1]));
    asm("v_cvt_pk_bf16_f32 %0, %1, %2" : "=v"(u1) : "v"(Sa[2]),  "v"(Sa[3]));
    asm("v_cvt_pk_bf16_f32 %0, %1, %2" : "=v"(u2) : "v"(Sa[4]),  "v"(Sa[5]));
    asm("v_cvt_pk_bf16_f32 %0, %1, %2" : "=v"(u3) : "v"(Sa[6]),  "v"(Sa[7]));
    asm("v_cvt_pk_bf16_f32 %0, %1, %2" : "=v"(u4) : "v"(Sa[8]),  "v"(Sa[9]));
    asm("v_cvt_pk_bf16_f32 %0, %1, %2" : "=v"(u5) : "v"(Sa[10]), "v"(Sa[11]));
    asm("v_cvt_pk_bf16_f32 %0, %1, %2" : "=v"(u6) : "v"(Sa[12]), "v"(Sa[13]));
    asm("v_cvt_pk_bf16_f32 %0, %1, %2" : "=v"(u7) : "v"(Sa[14]), "v"(Sa[15]));
    asm("v_permlane32_swap_b32 %0, %1" : "+v"(u0), "+v"(u2));
    asm("v_permlane32_swap_b32 %0, %1" : "+v"(u1), "+v"(u3));
    asm("v_permlane32_swap_b32 %0, %1" : "+v"(u4), "+v"(u6));
    asm("v_permlane32_swap_b32 %0, %1" : "+v"(u5), "+v"(u7));
    {
      uint4 fa0 = make_uint4(u0, u1, u2, u3);
      uint4 fa1 = make_uint4(u4, u5, u6, u7);
      a00 = mfma_bf16(__builtin_bit_cast(bf16x8, fa0), __builtin_bit_cast(bf16x8, g00), a00);
      a01 = mfma_bf16(__builtin_bit_cast(bf16x8, fa0), __builtin_bit_cast(bf16x8, g01), a01);
      a00 = mfma_bf16(__builtin_bit_cast(bf16x8, fa1), __builtin_bit_cast(bf16x8, g10), a00);
      a01 = mfma_bf16(__builtin_bit_cast(bf16x8, fa1), __builtin_bit_cast(bf16x8, g11), a01);
    }

    #pragma unroll
    for (int r = 0; r < 16; ++r) Sb[r] = fexp2(Sb[r]);
    asm("v_cvt_pk_bf16_f32 %0, %1, %2" : "=v"(u0) : "v"(Sb[0]),  "v"(Sb[1]));
    asm("v_cvt_pk_bf16_f32 %0, %1, %2" : "=v"(u1) : "v"(Sb[2]),  "v"(Sb[3]));
    asm("v_cvt_pk_bf16_f32 %0, %1, %2" : "=v"(u2) : "v"(Sb[4]),  "v"(Sb[5]));
    asm("v_cvt_pk_bf16_f32 %0, %1, %2" : "=v"(u3) : "v"(Sb[6]),  "v"(Sb[7]));
    asm("v_cvt_pk_bf16_f32 %0, %1, %2" : "=v"(u4) : "v"(Sb[8]),  "v"(Sb[9]));
    asm("v_cvt_pk_bf16_f32 %0, %1, %2" : "=v"(u5) : "v"(Sb[10]), "v"(Sb[11]));
    asm("v_cvt_pk_bf16_f32 %0, %1, %2" : "=v"(u6) : "v"(Sb[12]), "v"(Sb[13]));
    asm("v_cvt_pk_bf16_f32 %0, %1, %2" : "=v"(u7) : "v"(Sb[14]), "v"(Sb[15]));
    asm("v_permlane32_swap_b32 %0, %1" : "+v"(u0), "+v"(u2));
    asm("v_permlane32_swap_b32 %0, %1" : "+v"(u1), "+v"(u3));
    asm("v_permlane32_swap_b32 %0, %1" : "+v"(u4), "+v"(u6));
    asm("v_permlane32_swap_b32 %0, %1" : "+v"(u5), "+v"(u7));
    {
      uint4 fb0 = make_uint4(u0, u1, u2, u3);
      uint4 fb1 = make_uint4(u4, u5, u6, u7);
      a10 = mfma_bf16(__builtin_bit_cast(bf16x8, fb0), __builtin_bit_cast(bf16x8, g00), a10);
      a11 = mfma_bf16(__builtin_bit_cast(bf16x8, fb0), __builtin_bit_cast(bf16x8, g01), a11);
      a10 = mfma_bf16(__builtin_bit_cast(bf16x8, fb1), __builtin_bit_cast(bf16x8, g10), a10);
      a11 = mfma_bf16(__builtin_bit_cast(bf16x8, fb1), __builtin_bit_cast(bf16x8, g11), a11);
    }

    pA = pAn;
    g00 = n00; g01 = n01; g10 = n10; g11 = n11;
  }

  float ga = ldany(gamma, 0, f);
  float alpha = 1.f / (1.f + __expf(-ga));

  #pragma unroll
  for (int h = 0; h < 2; ++h) {
    __syncthreads();
    {
      f32x16 ac0 = (h == 0) ? a00 : a10;
      f32x16 ac1 = (h == 0) ? a01 : a11;
      #pragma unroll
      for (int r = 0; r < 16; ++r) {
        int qq = (r & 3) + 8 * (r >> 2) + 4 * lh;
        agPart[mq][qq][lr]      = ac0[r];
        agPart[mq][qq][32 + lr] = ac1[r];
      }
    }
    __syncthreads();
    {
      #pragma unroll
      for (int jj = 0; jj < 8; ++jj) {
        int c = mq * 16 + lh * 8 + jj;
        float vsum = agPart[0][lr][c] + agPart[1][lr][c] + agPart[2][lr][c] + agPart[3][lr][c];
        agF[lr][c] = f2bf(vsum);
      }
    }
    __syncthreads();
    {
      f32x16 oacc;
      #pragma unroll
      for (int i = 0; i < 16; ++i) oacc[i] = 0.f;
      #pragma unroll
      for (int ks = 0; ks < 4; ++ks) {
        bf16x8 aw = __builtin_bit_cast(bf16x8, wF_lds[mq * 4 + ks][l]);
        bf16x8 bg = __builtin_bit_cast(bf16x8, *(const uint4*)&agF[lr][ks * 16 + lh * 8]);
        oacc = mfma_bf16(aw, bg, oacc);
      }
      if (f) {
        float* o0 = (float*)out_base;
        float* o1 = o0 + NX;
        const float* xf = (const float*)x;
        #pragma unroll
        for (int r = 0; r < 16; ++r) {
          int o = mq * 32 + (r & 3) + 8 * (r >> 2) + 4 * lh;
          size_t oi = ((size_t)b * CH + o) * NQ + q0 + h * 32 + lr;
          float ag = oacc[r] + bag_sh[o];
          o0[oi] = (1.f - alpha) * xf[oi] + alpha * ag;
          o1[oi] = ag;
        }
      } else {
        ushort* o0 = (ushort*)out_base;
        ushort* o1 = o0 + NX;
        const ushort* xu = (const ushort*)x;
        #pragma unroll
        for (int r = 0; r < 16; ++r) {
          int o = mq * 32 + (r & 3) + 8 * (r >> 2) + 4 * lh;
          size_t oi = ((size_t)b * CH + o) * NQ + q0 + h * 32 + lr;
          float ag = oacc[r] + bag_sh[o];
          o0[oi] = f2bf((1.f - alpha) * bf2f(xu[oi]) + alpha * ag);
          o1[oi] = f2bf(ag);
        }
      }
    }
  }
}

extern "C" void kernel_launch(void* const* d_in, const int* in_sizes, int n_in,
                              void* d_out, int out_size, void* d_ws, size_t ws_size,
                              hipStream_t stream) {
  const void* x    = d_in[0];
  const void* wT   = d_in[1];
  const void* bT   = d_in[2];
  const void* wP   = d_in[3];
  const void* bP   = d_in[4];
  const void* wG   = d_in[5];
  const void* bG   = d_in[6];
  const void* wAG  = d_in[7];
  const void* bAG  = d_in[8];
  const void* gmm  = d_in[9];

  char* ws = (char*)d_ws;
  ushort* theta  = (ushort*)(ws + 0);          // 1 MB
  ushort* phi    = (ushort*)(ws + 1048576);    // 256 KB
  ushort* gm     = (ushort*)(ws + 1310720);    // 1 MB  [b][m][64] bf16
  uint4*  gsF    = (uint4*) (ws + 3407872);    // 1 MB  pre-swizzled PV B-frags

  k_proj<<<dim3(256, 2), dim3(256), 0, stream>>>(x, wT, bT, wP, bP, wG, bG, theta, phi, gm);
  k_denom2<<<dim3(128, 2), dim3(1024), 0, stream>>>(theta, phi, gm, gsF);
  k_attn<<<dim3(512), dim3(256), 0, stream>>>(theta, phi, gsF, wAG, bAG, x, gmm, d_out);
}

// Round 18
// 73.345 us; speedup vs baseline: 1.0844x; 1.0844x over previous
//
#include <hip/hip_runtime.h>

typedef short bf16x8 __attribute__((ext_vector_type(8)));
typedef float f32x16 __attribute__((ext_vector_type(16)));

#define DI __device__ __forceinline__

constexpr int BS = 2, CH = 128;
constexpr int NQ = 16384, NM = 4096;
constexpr size_t NX = (size_t)BS * CH * NQ;   // elements per output tensor

DI float bf2f(ushort u) { unsigned v = ((unsigned)u) << 16; return __builtin_bit_cast(float, v); }
DI ushort f2bf(float f) {
  unsigned u = __builtin_bit_cast(unsigned, f);
  u += 0x7FFFu + ((u >> 16) & 1u);   // RNE
  return (ushort)(u >> 16);
}
DI float ldany(const void* p, size_t i, int f) {
  return f ? ((const float*)p)[i] : bf2f(((const ushort*)p)[i]);
}
DI f32x16 mfma_bf16(bf16x8 a, bf16x8 b, f32x16 c) {
  return __builtin_amdgcn_mfma_f32_32x32x16_bf16(a, b, c, 0, 0, 0);
}
DI float fexp2(float x) { return __builtin_amdgcn_exp2f(x); }   // 1x v_exp_f32

DI int sniff_local(const void* x) {
  const ushort* u = (const ushort*)x;
  int garbage = 0, zeros = 0;
  for (int i = 0; i < 256; ++i) {
    float v = bf2f(u[i]);
    if (!(fabsf(v) < 1e9f)) garbage++;
    if ((i & 1) == 0 && u[i] == 0) zeros++;
  }
  return (garbage >= 8 || zeros >= 100) ? 1 : 0;   // 1 = f32 buffers
}

// ---------------- weight prep (flag computed per-block; block 0 publishes) ----
__global__ __launch_bounds__(256) void k_prep(
    const void* __restrict__ x,
    const void* __restrict__ wT, const void* __restrict__ bT,
    const void* __restrict__ wP, const void* __restrict__ bP,
    const void* __restrict__ wG, const void* __restrict__ bG,
    const void* __restrict__ wAG, const void* __restrict__ bAG,
    int* __restrict__ flag,
    float* __restrict__ bAllf, uint4* __restrict__ wF, uint4* __restrict__ wBf)
{
  int t = threadIdx.x;
  __shared__ int fsh;
  if (t == 0) {
    int f = sniff_local(x);
    fsh = f;
    if (blockIdx.x == 0) flag[0] = f;
  }
  __syncthreads();
  int f = fsh;

  if (blockIdx.x == 0) {
    if (t < 16)  bAllf[t]       = ldany(bT, t, f);
    if (t < 16)  bAllf[16 + t]  = ldany(bP, t, f);
    if (t < 64)  bAllf[32 + t]  = ldany(bG, t, f);
    if (t < 128) bAllf[96 + t]  = ldany(bAG, t, f);
  } else if (blockIdx.x <= 4) {
    int idx = (blockIdx.x - 1) * 256 + t;  // 0..1023
    int lane = idx & 63, ks = (idx >> 6) & 3, ot = idx >> 8;
    size_t src = (size_t)(ot * 32 + (lane & 31)) * 64 + ks * 16 + (lane >> 5) * 8;
    union { uint4 v4; ushort s[8]; } o;
    #pragma unroll
    for (int j = 0; j < 8; ++j) o.s[j] = f2bf(ldany(wAG, src + j, f));
    wF[idx] = o.v4;
  } else {
    int idx = (int)(blockIdx.x - 5) * 256 + t;  // 0..1535
    int kb = idx / 192, rem = idx % 192;
    int ob = rem >> 6, lane = rem & 63;
    int r = ob * 32 + (lane & 31);
    int c = kb * 16 + (lane >> 5) * 8;
    const void* src; int row;
    if (r < 16)      { src = wT; row = r; }
    else if (r < 32) { src = wP; row = r - 16; }
    else             { src = wG; row = r - 32; }
    union { uint4 v4; ushort s[8]; } o;
    #pragma unroll
    for (int j = 0; j < 8; ++j) o.s[j] = f2bf(ldany(src, (size_t)row * 128 + c + j, f));
    wBf[(kb * 3 + ob) * 64 + lane] = o.v4;
  }
}

// ---------------- projections via MFMA (K-split: 2 waves/SIMD occupancy) ------
__global__ __launch_bounds__(256) void k_proj(
    const void* __restrict__ x, const int* __restrict__ flag,
    const uint4* __restrict__ wBf, const float* __restrict__ bAllf,
    ushort* __restrict__ theta, ushort* __restrict__ phi, ushort* __restrict__ gm)
{
  int b = blockIdx.y;
  int qt = blockIdx.x;              // 0..255, 64 q each
  int t = threadIdx.x;
  int w = t >> 6, l = t & 63, lr = l & 31, lh = l >> 5;
  int qhalf = w & 1, khalf = w >> 1;
  int f = flag[0];

  __shared__ float tile[64][33];

  size_t xbase = (size_t)b * CH * NQ + qt * 64 + qhalf * 32 + lr;

  f32x16 acc0, acc1, acc2;
  #pragma unroll
  for (int i = 0; i < 16; ++i) { acc0[i] = 0.f; acc1[i] = 0.f; acc2[i] = 0.f; }

  #pragma unroll
  for (int kk = 0; kk < 4; ++kk) {
    int kb = khalf * 4 + kk;
    union { uint4 v4; ushort s[8]; } a;
    int cb = kb * 16 + lh * 8;
    if (f) {
      const float* xf = (const float*)x;
      #pragma unroll
      for (int j = 0; j < 8; ++j) a.s[j] = f2bf(xf[xbase + (size_t)(cb + j) * NQ]);
    } else {
      const ushort* xu = (const ushort*)x;
      #pragma unroll
      for (int j = 0; j < 8; ++j) a.s[j] = xu[xbase + (size_t)(cb + j) * NQ];
    }
    bf16x8 aF = __builtin_bit_cast(bf16x8, a.v4);
    uint4 b0 = wBf[(kb * 3 + 0) * 64 + l];
    uint4 b1 = wBf[(kb * 3 + 1) * 64 + l];
    uint4 b2 = wBf[(kb * 3 + 2) * 64 + l];
    acc0 = mfma_bf16(aF, __builtin_bit_cast(bf16x8, b0), acc0);
    acc1 = mfma_bf16(aF, __builtin_bit_cast(bf16x8, b1), acc1);
    acc2 = mfma_bf16(aF, __builtin_bit_cast(bf16x8, b2), acc2);
  }

  constexpr float L2E = 1.4426950408889634f;

  #pragma unroll
  for (int ob = 0; ob < 3; ++ob) {
    f32x16 A = (ob == 0) ? acc0 : ((ob == 1) ? acc1 : acc2);
    __syncthreads();
    if (khalf == 1) {
      #pragma unroll
      for (int r = 0; r < 16; ++r) {
        int qq = (r & 3) + 8 * (r >> 2) + 4 * lh;
        tile[qhalf * 32 + qq][lr] = A[r];
      }
    }
    __syncthreads();
    if (khalf == 0) {
      #pragma unroll
      for (int r = 0; r < 16; ++r) {
        int qq = (r & 3) + 8 * (r >> 2) + 4 * lh;
        tile[qhalf * 32 + qq][lr] += A[r];
      }
    }
    __syncthreads();
    if (ob == 0) {
      if (t < 64) {                      // theta
        union { uint4 v4[2]; ushort s[16]; } th;
        #pragma unroll
        for (int c = 0; c < 16; ++c)
          th.s[c] = f2bf(tanhf(tile[t][c] + bAllf[c]) * L2E);
        uint4* dst = (uint4*)(theta + ((size_t)b * NQ + qt * 64 + t) * 16);
        dst[0] = th.v4[0]; dst[1] = th.v4[1];
      } else if (t < 128) {              // phi
        int idx = t - 64;
        int m = idx >> 2, c4 = (idx & 3) * 4;
        int h2 = m * 2;
        union { uint2 v2; ushort s[4]; } ph;
        #pragma unroll
        for (int cc = 0; cc < 4; ++cc) {
          int c = 16 + c4 + cc;
          float z = fmaxf(fmaxf(tile[h2][c], tile[h2 + 1][c]),
                          fmaxf(tile[32 + h2][c], tile[32 + h2 + 1][c]));
          ph.s[cc] = f2bf(tanhf(z + bAllf[c]));
        }
        *(uint2*)(phi + ((size_t)b * NM + qt * 16 + m) * 16 + c4) = ph.v2;
      }
    } else {                             // g
      if (t < 128) {
        int cb = (ob - 1) * 32;
        int m = t >> 3, c4 = (t & 7) * 4;
        int h2 = m * 2;
        union { uint2 v2; ushort s[4]; } gv;
        #pragma unroll
        for (int cc = 0; cc < 4; ++cc) {
          int c = c4 + cc;
          float z = fmaxf(fmaxf(tile[h2][c], tile[h2 + 1][c]),
                          fmaxf(tile[32 + h2][c], tile[32 + h2 + 1][c]));
          gv.s[cc] = f2bf(z + bAllf[32 + cb + c]);
        }
        *(uint2*)(gm + ((size_t)b * NM + qt * 16 + m) * 64 + cb + c4) = gv.v2;
      }
    }
  }
}

// ---------------- denominator + scale + PV B-frag pack (merged) ----------------
__global__ __launch_bounds__(1024, 2) void k_denom2(
    const ushort* __restrict__ theta, const ushort* __restrict__ phi,
    const ushort* __restrict__ gm, uint4* __restrict__ gsF)
{
  int b = blockIdx.y, mb = blockIdx.x;   // 128 chunks of 32 m
  int t = threadIdx.x;
  int w = t >> 6, l = t & 63, lr = l & 31, lh = l >> 5;
  int mbase = mb * 32;

  __shared__ float part[16][33];
  __shared__ float dinv_sh[32];
  __shared__ float tile[32][65];

  bf16x8 pB = __builtin_bit_cast(bf16x8, *(const uint4*)(phi + ((size_t)b * NM + mbase + lr) * 16 + lh * 8));
  const ushort* thb = theta + ((size_t)b * NQ + w * 1024 + lr) * 16 + lh * 8;

  bf16x8 tA1 = __builtin_bit_cast(bf16x8, *(const uint4*)(thb + 512));
  f32x16 S;
  #pragma unroll
  for (int i = 0; i < 16; ++i) S[i] = 0.f;
  S = mfma_bf16(__builtin_bit_cast(bf16x8, *(const uint4*)thb), pB, S);

  float s = 0.f;
  for (int it = 0; it < 32; ++it) {
    bf16x8 tA2 = __builtin_bit_cast(bf16x8, *(const uint4*)(thb + (size_t)((it + 2) & 31) * 512));
    __builtin_amdgcn_sched_barrier(0);
    f32x16 Sn;
    #pragma unroll
    for (int i = 0; i < 16; ++i) Sn[i] = 0.f;
    Sn = mfma_bf16(tA1, pB, Sn);          // next tile's S overlaps this exp block
    #pragma unroll
    for (int r = 0; r < 16; ++r) s += fexp2(S[r]);
    S = Sn; tA1 = tA2;
  }
  s += __shfl_xor(s, 32, 64);
  if (l < 32) part[w][lr] = s;
  __syncthreads();

  if (t < 32) {
    float d = 0.f;
    #pragma unroll
    for (int p = 0; p < 16; ++p) d += part[p][t];
    dinv_sh[t] = 1.f / d;
  }
  __syncthreads();

  if (t < 256) {
    int m_loc = t >> 3, c = (t & 7) * 8;
    union { uint4 v4; ushort s[8]; } v;
    v.v4 = *(const uint4*)(gm + ((size_t)b * NM + mbase + m_loc) * 64 + c);
    float dv = dinv_sh[m_loc];
    #pragma unroll
    for (int j = 0; j < 8; ++j) tile[m_loc][c + j] = bf2f(v.s[j]) * dv;
  }
  __syncthreads();

  if (t < 256) {
    int ms_loc = t >> 7, ct = (t >> 6) & 1, lane = t & 63;
    int col = ct * 32 + (lane & 31);
    int rbase = ms_loc * 16 + (lane >> 5) * 8;
    union { uint4 v4; ushort s[8]; } o;
    #pragma unroll
    for (int j = 0; j < 8; ++j) o.s[j] = f2bf(tile[rbase + j][col]);
    int ms = (mbase >> 4) + ms_loc;
    gsF[(((size_t)b * 256 + ms) * 2 + ct) * 64 + lane] = o.v4;
  }
}

// ---------------- fused attention + output (R13 champion) ----------------
__global__ __launch_bounds__(256, 3) void k_attn(
    const ushort* __restrict__ theta, const ushort* __restrict__ phi,
    const uint4* __restrict__ gsF, const uint4* __restrict__ wF,
    const float* __restrict__ bAllf, const void* __restrict__ x,
    const void* __restrict__ gamma, const int* __restrict__ flag,
    void* __restrict__ out_base)
{
  int b = blockIdx.y;
  int q0 = blockIdx.x * 64;
  int t = threadIdx.x;
  int mq = t >> 6, l = t & 63, lr = l & 31, lh = l >> 5;

  __shared__ float agPart[4][32][65];
  __shared__ __align__(16) ushort agF[32][80];

  bf16x8 tB0 = __builtin_bit_cast(bf16x8, *(const uint4*)(theta + ((size_t)b * NQ + q0 + lr) * 16 + lh * 8));
  bf16x8 tB1 = __builtin_bit_cast(bf16x8, *(const uint4*)(theta + ((size_t)b * NQ + q0 + 32 + lr) * 16 + lh * 8));

  const ushort* phb = phi + ((size_t)b * NM + lr) * 16 + lh * 8;
  const uint4* gF = gsF + (size_t)b * 32768;

  f32x16 a00, a01, a10, a11;
  #pragma unroll
  for (int i = 0; i < 16; ++i) { a00[i] = 0.f; a01[i] = 0.f; a10[i] = 0.f; a11[i] = 0.f; }
  f32x16 zero16;
  #pragma unroll
  for (int i = 0; i < 16; ++i) zero16[i] = 0.f;

  size_t gb0 = (size_t)(mq * 2) * 128;
  uint4 g00 = gF[gb0 + l];
  uint4 g01 = gF[gb0 + 64 + l];
  uint4 g10 = gF[gb0 + 128 + l];
  uint4 g11 = gF[gb0 + 192 + l];
  bf16x8 pA = __builtin_bit_cast(bf16x8, *(const uint4*)(phb + (size_t)(mq * 32) * 16));

  for (int it = 0; it < 32; ++it) {
    int it1 = (it + 1) & 31;
    size_t gb = (size_t)(mq * 2 + it1 * 8) * 128;
    uint4 n00 = gF[gb + l];
    uint4 n01 = gF[gb + 64 + l];
    uint4 n10 = gF[gb + 128 + l];
    uint4 n11 = gF[gb + 192 + l];
    bf16x8 pAn = __builtin_bit_cast(bf16x8, *(const uint4*)(phb + (size_t)(mq * 32 + it1 * 128) * 16));
    __builtin_amdgcn_sched_barrier(0);

    f32x16 Sa = mfma_bf16(pA, tB0, zero16);
    f32x16 Sb = mfma_bf16(pA, tB1, zero16);

    uint u0, u1, u2, u3, u4, u5, u6, u7;

    #pragma unroll
    for (int r = 0; r < 16; ++r) Sa[r] = fexp2(Sa[r]);
    asm("v_cvt_pk_bf16_f32 %0, %1, %2" : "=v"(u0) : "v"(Sa[0]),  "v"(Sa[1]));
    asm("v_cvt_pk_bf16_f32 %0, %1, %2" : "=v"(u1) : "v"(Sa[2]),  "v"(Sa[3]));
    asm("v_cvt_pk_bf16_f32 %0, %1, %2" : "=v"(u2) : "v"(Sa[4]),  "v"(Sa[5]));
    asm("v_cvt_pk_bf16_f32 %0, %1, %2" : "=v"(u3) : "v"(Sa[6]),  "v"(Sa[7]));
    asm("v_cvt_pk_bf16_f32 %0, %1, %2" : "=v"(u4) : "v"(Sa[8]),  "v"(Sa[9]));
    asm("v_cvt_pk_bf16_f32 %0, %1, %2" : "=v"(u5) : "v"(Sa[10]), "v"(Sa[11]));
    asm("v_cvt_pk_bf16_f32 %0, %1, %2" : "=v"(u6) : "v"(Sa[12]), "v"(Sa[13]));
    asm("v_cvt_pk_bf16_f32 %0, %1, %2" : "=v"(u7) : "v"(Sa[14]), "v"(Sa[15]));
    asm("v_permlane32_swap_b32 %0, %1" : "+v"(u0), "+v"(u2));
    asm("v_permlane32_swap_b32 %0, %1" : "+v"(u1), "+v"(u3));
    asm("v_permlane32_swap_b32 %0, %1" : "+v"(u4), "+v"(u6));
    asm("v_permlane32_swap_b32 %0, %1" : "+v"(u5), "+v"(u7));
    {
      uint4 fa0 = make_uint4(u0, u1, u2, u3);
      uint4 fa1 = make_uint4(u4, u5, u6, u7);
      a00 = mfma_bf16(__builtin_bit_cast(bf16x8, fa0), __builtin_bit_cast(bf16x8, g00), a00);
      a01 = mfma_bf16(__builtin_bit_cast(bf16x8, fa0), __builtin_bit_cast(bf16x8, g01), a01);
      a00 = mfma_bf16(__builtin_bit_cast(bf16x8, fa1), __builtin_bit_cast(bf16x8, g10), a00);
      a01 = mfma_bf16(__builtin_bit_cast(bf16x8, fa1), __builtin_bit_cast(bf16x8, g11), a01);
    }

    #pragma unroll
    for (int r = 0; r < 16; ++r) Sb[r] = fexp2(Sb[r]);
    asm("v_cvt_pk_bf16_f32 %0, %1, %2" : "=v"(u0) : "v"(Sb[0]),  "v"(Sb[1]));
    asm("v_cvt_pk_bf16_f32 %0, %1, %2" : "=v"(u1) : "v"(Sb[2]),  "v"(Sb[3]));
    asm("v_cvt_pk_bf16_f32 %0, %1, %2" : "=v"(u2) : "v"(Sb[4]),  "v"(Sb[5]));
    asm("v_cvt_pk_bf16_f32 %0, %1, %2" : "=v"(u3) : "v"(Sb[6]),  "v"(Sb[7]));
    asm("v_cvt_pk_bf16_f32 %0, %1, %2" : "=v"(u4) : "v"(Sb[8]),  "v"(Sb[9]));
    asm("v_cvt_pk_bf16_f32 %0, %1, %2" : "=v"(u5) : "v"(Sb[10]), "v"(Sb[11]));
    asm("v_cvt_pk_bf16_f32 %0, %1, %2" : "=v"(u6) : "v"(Sb[12]), "v"(Sb[13]));
    asm("v_cvt_pk_bf16_f32 %0, %1, %2" : "=v"(u7) : "v"(Sb[14]), "v"(Sb[15]));
    asm("v_permlane32_swap_b32 %0, %1" : "+v"(u0), "+v"(u2));
    asm("v_permlane32_swap_b32 %0, %1" : "+v"(u1), "+v"(u3));
    asm("v_permlane32_swap_b32 %0, %1" : "+v"(u4), "+v"(u6));
    asm("v_permlane32_swap_b32 %0, %1" : "+v"(u5), "+v"(u7));
    {
      uint4 fb0 = make_uint4(u0, u1, u2, u3);
      uint4 fb1 = make_uint4(u4, u5, u6, u7);
      a10 = mfma_bf16(__builtin_bit_cast(bf16x8, fb0), __builtin_bit_cast(bf16x8, g00), a10);
      a11 = mfma_bf16(__builtin_bit_cast(bf16x8, fb0), __builtin_bit_cast(bf16x8, g01), a11);
      a10 = mfma_bf16(__builtin_bit_cast(bf16x8, fb1), __builtin_bit_cast(bf16x8, g10), a10);
      a11 = mfma_bf16(__builtin_bit_cast(bf16x8, fb1), __builtin_bit_cast(bf16x8, g11), a11);
    }

    pA = pAn;
    g00 = n00; g01 = n01; g10 = n10; g11 = n11;
  }

  int mode = flag[0];
  float ga = ldany(gamma, 0, mode);
  float alpha = 1.f / (1.f + __expf(-ga));

  #pragma unroll
  for (int h = 0; h < 2; ++h) {
    __syncthreads();
    {
      f32x16 ac0 = (h == 0) ? a00 : a10;
      f32x16 ac1 = (h == 0) ? a01 : a11;
      #pragma unroll
      for (int r = 0; r < 16; ++r) {
        int qq = (r & 3) + 8 * (r >> 2) + 4 * lh;
        agPart[mq][qq][lr]      = ac0[r];
        agPart[mq][qq][32 + lr] = ac1[r];
      }
    }
    __syncthreads();
    {
      #pragma unroll
      for (int jj = 0; jj < 8; ++jj) {
        int c = mq * 16 + lh * 8 + jj;
        float vsum = agPart[0][lr][c] + agPart[1][lr][c] + agPart[2][lr][c] + agPart[3][lr][c];
        agF[lr][c] = f2bf(vsum);
      }
    }
    __syncthreads();
    {
      f32x16 oacc;
      #pragma unroll
      for (int i = 0; i < 16; ++i) oacc[i] = 0.f;
      #pragma unroll
      for (int ks = 0; ks < 4; ++ks) {
        bf16x8 aw = __builtin_bit_cast(bf16x8, wF[(mq * 4 + ks) * 64 + l]);
        bf16x8 bg = __builtin_bit_cast(bf16x8, *(const uint4*)&agF[lr][ks * 16 + lh * 8]);
        oacc = mfma_bf16(aw, bg, oacc);
      }
      if (mode) {
        float* o0 = (float*)out_base;
        float* o1 = o0 + NX;
        const float* xf = (const float*)x;
        #pragma unroll
        for (int r = 0; r < 16; ++r) {
          int o = mq * 32 + (r & 3) + 8 * (r >> 2) + 4 * lh;
          size_t oi = ((size_t)b * CH + o) * NQ + q0 + h * 32 + lr;
          float ag = oacc[r] + bAllf[96 + o];
          o0[oi] = (1.f - alpha) * xf[oi] + alpha * ag;
          o1[oi] = ag;
        }
      } else {
        ushort* o0 = (ushort*)out_base;
        ushort* o1 = o0 + NX;
        const ushort* xu = (const ushort*)x;
        #pragma unroll
        for (int r = 0; r < 16; ++r) {
          int o = mq * 32 + (r & 3) + 8 * (r >> 2) + 4 * lh;
          size_t oi = ((size_t)b * CH + o) * NQ + q0 + h * 32 + lr;
          float ag = oacc[r] + bAllf[96 + o];
          o0[oi] = f2bf((1.f - alpha) * bf2f(xu[oi]) + alpha * ag);
          o1[oi] = f2bf(ag);
        }
      }
    }
  }
}

extern "C" void kernel_launch(void* const* d_in, const int* in_sizes, int n_in,
                              void* d_out, int out_size, void* d_ws, size_t ws_size,
                              hipStream_t stream) {
  const void* x    = d_in[0];
  const void* wT   = d_in[1];
  const void* bT   = d_in[2];
  const void* wP   = d_in[3];
  const void* bP   = d_in[4];
  const void* wG   = d_in[5];
  const void* bG   = d_in[6];
  const void* wAG  = d_in[7];
  const void* bAG  = d_in[8];
  const void* gmm  = d_in[9];

  char* ws = (char*)d_ws;
  ushort* theta  = (ushort*)(ws + 0);          // 1 MB
  ushort* phi    = (ushort*)(ws + 1048576);    // 256 KB
  ushort* gm     = (ushort*)(ws + 1310720);    // 1 MB  [b][m][64] bf16
  uint4*  gsF    = (uint4*) (ws + 3407872);    // 1 MB  pre-swizzled PV B-frags
  uint4*  wF     = (uint4*) (ws + 4456448);    // 16 KB
  uint4*  wBf    = (uint4*) (ws + 4472832);    // 24 KB k_proj B-frags
  float*  bAllf  = (float*) (ws + 4497408);    // 1 KB
  int*    flag   = (int*)   (ws + 4498432);    // 4 B

  k_prep<<<dim3(11), dim3(256), 0, stream>>>(x, wT, bT, wP, bP, wG, bG, wAG, bAG, flag, bAllf, wF, wBf);
  k_proj<<<dim3(256, 2), dim3(256), 0, stream>>>(x, flag, wBf, bAllf, theta, phi, gm);
  k_denom2<<<dim3(128, 2), dim3(1024), 0, stream>>>(theta, phi, gm, gsF);
  k_attn<<<dim3(256, 2), dim3(256), 0, stream>>>(theta, phi, gsF, wF, bAllf, x, gmm, flag, d_out);
}

// Round 19
// 73.093 us; speedup vs baseline: 1.0882x; 1.0034x over previous
//
#include <hip/hip_runtime.h>

typedef short bf16x8 __attribute__((ext_vector_type(8)));
typedef float f32x16 __attribute__((ext_vector_type(16)));

#define DI __device__ __forceinline__

constexpr int BS = 2, CH = 128;
constexpr int NQ = 16384, NM = 4096;
constexpr size_t NX = (size_t)BS * CH * NQ;   // elements per output tensor

DI float bf2f(ushort u) { unsigned v = ((unsigned)u) << 16; return __builtin_bit_cast(float, v); }
DI ushort f2bf(float f) {
  unsigned u = __builtin_bit_cast(unsigned, f);
  u += 0x7FFFu + ((u >> 16) & 1u);   // RNE
  return (ushort)(u >> 16);
}
DI float ldany(const void* p, size_t i, int f) {
  return f ? ((const float*)p)[i] : bf2f(((const ushort*)p)[i]);
}
DI f32x16 mfma_bf16(bf16x8 a, bf16x8 b, f32x16 c) {
  return __builtin_amdgcn_mfma_f32_32x32x16_bf16(a, b, c, 0, 0, 0);
}
DI float fexp2(float x) { return __builtin_amdgcn_exp2f(x); }   // 1x v_exp_f32

DI int sniff_local(const void* x) {
  const ushort* u = (const ushort*)x;
  int garbage = 0, zeros = 0;
  for (int i = 0; i < 256; ++i) {
    float v = bf2f(u[i]);
    if (!(fabsf(v) < 1e9f)) garbage++;
    if ((i & 1) == 0 && u[i] == 0) zeros++;
  }
  return (garbage >= 8 || zeros >= 100) ? 1 : 0;   // 1 = f32 buffers
}

// ---------------- weight prep (flag computed per-block; block 0 publishes) ----
__global__ __launch_bounds__(256) void k_prep(
    const void* __restrict__ x,
    const void* __restrict__ wT, const void* __restrict__ bT,
    const void* __restrict__ wP, const void* __restrict__ bP,
    const void* __restrict__ wG, const void* __restrict__ bG,
    const void* __restrict__ wAG, const void* __restrict__ bAG,
    int* __restrict__ flag,
    float* __restrict__ bAllf, uint4* __restrict__ wF, uint4* __restrict__ wBf)
{
  int t = threadIdx.x;
  __shared__ int fsh;
  if (t == 0) {
    int f = sniff_local(x);
    fsh = f;
    if (blockIdx.x == 0) flag[0] = f;
  }
  __syncthreads();
  int f = fsh;

  if (blockIdx.x == 0) {
    if (t < 16)  bAllf[t]       = ldany(bT, t, f);
    if (t < 16)  bAllf[16 + t]  = ldany(bP, t, f);
    if (t < 64)  bAllf[32 + t]  = ldany(bG, t, f);
    if (t < 128) bAllf[96 + t]  = ldany(bAG, t, f);
  } else if (blockIdx.x <= 4) {
    int idx = (blockIdx.x - 1) * 256 + t;  // 0..1023
    int lane = idx & 63, ks = (idx >> 6) & 3, ot = idx >> 8;
    size_t src = (size_t)(ot * 32 + (lane & 31)) * 64 + ks * 16 + (lane >> 5) * 8;
    union { uint4 v4; ushort s[8]; } o;
    #pragma unroll
    for (int j = 0; j < 8; ++j) o.s[j] = f2bf(ldany(wAG, src + j, f));
    wF[idx] = o.v4;
  } else {
    int idx = (int)(blockIdx.x - 5) * 256 + t;  // 0..1535
    int kb = idx / 192, rem = idx % 192;
    int ob = rem >> 6, lane = rem & 63;
    int r = ob * 32 + (lane & 31);
    int c = kb * 16 + (lane >> 5) * 8;
    const void* src; int row;
    if (r < 16)      { src = wT; row = r; }
    else if (r < 32) { src = wP; row = r - 16; }
    else             { src = wG; row = r - 32; }
    union { uint4 v4; ushort s[8]; } o;
    #pragma unroll
    for (int j = 0; j < 8; ++j) o.s[j] = f2bf(ldany(src, (size_t)row * 128 + c + j, f));
    wBf[(kb * 3 + ob) * 64 + lane] = o.v4;
  }
}

// ---------------- projections via MFMA (K-split: 2 waves/SIMD occupancy) ------
__global__ __launch_bounds__(256) void k_proj(
    const void* __restrict__ x, const int* __restrict__ flag,
    const uint4* __restrict__ wBf, const float* __restrict__ bAllf,
    ushort* __restrict__ theta, ushort* __restrict__ phi, ushort* __restrict__ gm)
{
  int b = blockIdx.y;
  int qt = blockIdx.x;              // 0..255, 64 q each
  int t = threadIdx.x;
  int w = t >> 6, l = t & 63, lr = l & 31, lh = l >> 5;
  int qhalf = w & 1, khalf = w >> 1;
  int f = flag[0];

  __shared__ float tile[64][33];

  size_t xbase = (size_t)b * CH * NQ + qt * 64 + qhalf * 32 + lr;

  f32x16 acc0, acc1, acc2;
  #pragma unroll
  for (int i = 0; i < 16; ++i) { acc0[i] = 0.f; acc1[i] = 0.f; acc2[i] = 0.f; }

  #pragma unroll
  for (int kk = 0; kk < 4; ++kk) {
    int kb = khalf * 4 + kk;
    union { uint4 v4; ushort s[8]; } a;
    int cb = kb * 16 + lh * 8;
    if (f) {
      const float* xf = (const float*)x;
      #pragma unroll
      for (int j = 0; j < 8; ++j) a.s[j] = f2bf(xf[xbase + (size_t)(cb + j) * NQ]);
    } else {
      const ushort* xu = (const ushort*)x;
      #pragma unroll
      for (int j = 0; j < 8; ++j) a.s[j] = xu[xbase + (size_t)(cb + j) * NQ];
    }
    bf16x8 aF = __builtin_bit_cast(bf16x8, a.v4);
    uint4 b0 = wBf[(kb * 3 + 0) * 64 + l];
    uint4 b1 = wBf[(kb * 3 + 1) * 64 + l];
    uint4 b2 = wBf[(kb * 3 + 2) * 64 + l];
    acc0 = mfma_bf16(aF, __builtin_bit_cast(bf16x8, b0), acc0);
    acc1 = mfma_bf16(aF, __builtin_bit_cast(bf16x8, b1), acc1);
    acc2 = mfma_bf16(aF, __builtin_bit_cast(bf16x8, b2), acc2);
  }

  constexpr float L2E = 1.4426950408889634f;

  #pragma unroll
  for (int ob = 0; ob < 3; ++ob) {
    f32x16 A = (ob == 0) ? acc0 : ((ob == 1) ? acc1 : acc2);
    __syncthreads();
    if (khalf == 1) {
      #pragma unroll
      for (int r = 0; r < 16; ++r) {
        int qq = (r & 3) + 8 * (r >> 2) + 4 * lh;
        tile[qhalf * 32 + qq][lr] = A[r];
      }
    }
    __syncthreads();
    if (khalf == 0) {
      #pragma unroll
      for (int r = 0; r < 16; ++r) {
        int qq = (r & 3) + 8 * (r >> 2) + 4 * lh;
        tile[qhalf * 32 + qq][lr] += A[r];
      }
    }
    __syncthreads();
    if (ob == 0) {
      if (t < 64) {                      // theta
        union { uint4 v4[2]; ushort s[16]; } th;
        #pragma unroll
        for (int c = 0; c < 16; ++c)
          th.s[c] = f2bf(tanhf(tile[t][c] + bAllf[c]) * L2E);
        uint4* dst = (uint4*)(theta + ((size_t)b * NQ + qt * 64 + t) * 16);
        dst[0] = th.v4[0]; dst[1] = th.v4[1];
      } else if (t < 128) {              // phi
        int idx = t - 64;
        int m = idx >> 2, c4 = (idx & 3) * 4;
        int h2 = m * 2;
        union { uint2 v2; ushort s[4]; } ph;
        #pragma unroll
        for (int cc = 0; cc < 4; ++cc) {
          int c = 16 + c4 + cc;
          float z = fmaxf(fmaxf(tile[h2][c], tile[h2 + 1][c]),
                          fmaxf(tile[32 + h2][c], tile[32 + h2 + 1][c]));
          ph.s[cc] = f2bf(tanhf(z + bAllf[c]));
        }
        *(uint2*)(phi + ((size_t)b * NM + qt * 16 + m) * 16 + c4) = ph.v2;
      }
    } else {                             // g
      if (t < 128) {
        int cb = (ob - 1) * 32;
        int m = t >> 3, c4 = (t & 7) * 4;
        int h2 = m * 2;
        union { uint2 v2; ushort s[4]; } gv;
        #pragma unroll
        for (int cc = 0; cc < 4; ++cc) {
          int c = c4 + cc;
          float z = fmaxf(fmaxf(tile[h2][c], tile[h2 + 1][c]),
                          fmaxf(tile[32 + h2][c], tile[32 + h2 + 1][c]));
          gv.s[cc] = f2bf(z + bAllf[32 + cb + c]);
        }
        *(uint2*)(gm + ((size_t)b * NM + qt * 16 + m) * 64 + cb + c4) = gv.v2;
      }
    }
  }
}

// ---------------- denominator + scale + PV B-frag pack (merged) ----------------
__global__ __launch_bounds__(1024, 2) void k_denom2(
    const ushort* __restrict__ theta, const ushort* __restrict__ phi,
    const ushort* __restrict__ gm, uint4* __restrict__ gsF)
{
  int b = blockIdx.y, mb = blockIdx.x;   // 128 chunks of 32 m
  int t = threadIdx.x;
  int w = t >> 6, l = t & 63, lr = l & 31, lh = l >> 5;
  int mbase = mb * 32;

  __shared__ float part[16][33];
  __shared__ float dinv_sh[32];
  __shared__ float tile[32][65];

  bf16x8 pB = __builtin_bit_cast(bf16x8, *(const uint4*)(phi + ((size_t)b * NM + mbase + lr) * 16 + lh * 8));
  const ushort* thb = theta + ((size_t)b * NQ + w * 1024 + lr) * 16 + lh * 8;

  bf16x8 tA1 = __builtin_bit_cast(bf16x8, *(const uint4*)(thb + 512));
  f32x16 S;
  #pragma unroll
  for (int i = 0; i < 16; ++i) S[i] = 0.f;
  S = mfma_bf16(__builtin_bit_cast(bf16x8, *(const uint4*)thb), pB, S);

  float s = 0.f;
  for (int it = 0; it < 32; ++it) {
    bf16x8 tA2 = __builtin_bit_cast(bf16x8, *(const uint4*)(thb + (size_t)((it + 2) & 31) * 512));
    __builtin_amdgcn_sched_barrier(0);
    f32x16 Sn;
    #pragma unroll
    for (int i = 0; i < 16; ++i) Sn[i] = 0.f;
    Sn = mfma_bf16(tA1, pB, Sn);          // next tile's S overlaps this exp block
    #pragma unroll
    for (int r = 0; r < 16; ++r) s += fexp2(S[r]);
    S = Sn; tA1 = tA2;
  }
  s += __shfl_xor(s, 32, 64);
  if (l < 32) part[w][lr] = s;
  __syncthreads();

  if (t < 32) {
    float d = 0.f;
    #pragma unroll
    for (int p = 0; p < 16; ++p) d += part[p][t];
    dinv_sh[t] = 1.f / d;
  }
  __syncthreads();

  if (t < 256) {
    int m_loc = t >> 3, c = (t & 7) * 8;
    union { uint4 v4; ushort s[8]; } v;
    v.v4 = *(const uint4*)(gm + ((size_t)b * NM + mbase + m_loc) * 64 + c);
    float dv = dinv_sh[m_loc];
    #pragma unroll
    for (int j = 0; j < 8; ++j) tile[m_loc][c + j] = bf2f(v.s[j]) * dv;
  }
  __syncthreads();

  if (t < 256) {
    int ms_loc = t >> 7, ct = (t >> 6) & 1, lane = t & 63;
    int col = ct * 32 + (lane & 31);
    int rbase = ms_loc * 16 + (lane >> 5) * 8;
    union { uint4 v4; ushort s[8]; } o;
    #pragma unroll
    for (int j = 0; j < 8; ++j) o.s[j] = f2bf(tile[rbase + j][col]);
    int ms = (mbase >> 4) + ms_loc;
    gsF[(((size_t)b * 256 + ms) * 2 + ct) * 64 + lane] = o.v4;
  }
}

// ---------------- fused attention + output (R13 champion) ----------------
__global__ __launch_bounds__(256, 3) void k_attn(
    const ushort* __restrict__ theta, const ushort* __restrict__ phi,
    const uint4* __restrict__ gsF, const uint4* __restrict__ wF,
    const float* __restrict__ bAllf, const void* __restrict__ x,
    const void* __restrict__ gamma, const int* __restrict__ flag,
    void* __restrict__ out_base)
{
  int b = blockIdx.y;
  int q0 = blockIdx.x * 64;
  int t = threadIdx.x;
  int mq = t >> 6, l = t & 63, lr = l & 31, lh = l >> 5;

  __shared__ float agPart[4][32][65];
  __shared__ __align__(16) ushort agF[32][80];

  bf16x8 tB0 = __builtin_bit_cast(bf16x8, *(const uint4*)(theta + ((size_t)b * NQ + q0 + lr) * 16 + lh * 8));
  bf16x8 tB1 = __builtin_bit_cast(bf16x8, *(const uint4*)(theta + ((size_t)b * NQ + q0 + 32 + lr) * 16 + lh * 8));

  const ushort* phb = phi + ((size_t)b * NM + lr) * 16 + lh * 8;
  const uint4* gF = gsF + (size_t)b * 32768;

  f32x16 a00, a01, a10, a11;
  #pragma unroll
  for (int i = 0; i < 16; ++i) { a00[i] = 0.f; a01[i] = 0.f; a10[i] = 0.f; a11[i] = 0.f; }
  f32x16 zero16;
  #pragma unroll
  for (int i = 0; i < 16; ++i) zero16[i] = 0.f;

  size_t gb0 = (size_t)(mq * 2) * 128;
  uint4 g00 = gF[gb0 + l];
  uint4 g01 = gF[gb0 + 64 + l];
  uint4 g10 = gF[gb0 + 128 + l];
  uint4 g11 = gF[gb0 + 192 + l];
  bf16x8 pA = __builtin_bit_cast(bf16x8, *(const uint4*)(phb + (size_t)(mq * 32) * 16));

  for (int it = 0; it < 32; ++it) {
    int it1 = (it + 1) & 31;
    size_t gb = (size_t)(mq * 2 + it1 * 8) * 128;
    uint4 n00 = gF[gb + l];
    uint4 n01 = gF[gb + 64 + l];
    uint4 n10 = gF[gb + 128 + l];
    uint4 n11 = gF[gb + 192 + l];
    bf16x8 pAn = __builtin_bit_cast(bf16x8, *(const uint4*)(phb + (size_t)(mq * 32 + it1 * 128) * 16));
    __builtin_amdgcn_sched_barrier(0);

    f32x16 Sa = mfma_bf16(pA, tB0, zero16);
    f32x16 Sb = mfma_bf16(pA, tB1, zero16);

    uint u0, u1, u2, u3, u4, u5, u6, u7;

    #pragma unroll
    for (int r = 0; r < 16; ++r) Sa[r] = fexp2(Sa[r]);
    asm("v_cvt_pk_bf16_f32 %0, %1, %2" : "=v"(u0) : "v"(Sa[0]),  "v"(Sa[1]));
    asm("v_cvt_pk_bf16_f32 %0, %1, %2" : "=v"(u1) : "v"(Sa[2]),  "v"(Sa[3]));
    asm("v_cvt_pk_bf16_f32 %0, %1, %2" : "=v"(u2) : "v"(Sa[4]),  "v"(Sa[5]));
    asm("v_cvt_pk_bf16_f32 %0, %1, %2" : "=v"(u3) : "v"(Sa[6]),  "v"(Sa[7]));
    asm("v_cvt_pk_bf16_f32 %0, %1, %2" : "=v"(u4) : "v"(Sa[8]),  "v"(Sa[9]));
    asm("v_cvt_pk_bf16_f32 %0, %1, %2" : "=v"(u5) : "v"(Sa[10]), "v"(Sa[11]));
    asm("v_cvt_pk_bf16_f32 %0, %1, %2" : "=v"(u6) : "v"(Sa[12]), "v"(Sa[13]));
    asm("v_cvt_pk_bf16_f32 %0, %1, %2" : "=v"(u7) : "v"(Sa[14]), "v"(Sa[15]));
    asm("v_permlane32_swap_b32 %0, %1" : "+v"(u0), "+v"(u2));
    asm("v_permlane32_swap_b32 %0, %1" : "+v"(u1), "+v"(u3));
    asm("v_permlane32_swap_b32 %0, %1" : "+v"(u4), "+v"(u6));
    asm("v_permlane32_swap_b32 %0, %1" : "+v"(u5), "+v"(u7));
    {
      uint4 fa0 = make_uint4(u0, u1, u2, u3);
      uint4 fa1 = make_uint4(u4, u5, u6, u7);
      a00 = mfma_bf16(__builtin_bit_cast(bf16x8, fa0), __builtin_bit_cast(bf16x8, g00), a00);
      a01 = mfma_bf16(__builtin_bit_cast(bf16x8, fa0), __builtin_bit_cast(bf16x8, g01), a01);
      a00 = mfma_bf16(__builtin_bit_cast(bf16x8, fa1), __builtin_bit_cast(bf16x8, g10), a00);
      a01 = mfma_bf16(__builtin_bit_cast(bf16x8, fa1), __builtin_bit_cast(bf16x8, g11), a01);
    }

    #pragma unroll
    for (int r = 0; r < 16; ++r) Sb[r] = fexp2(Sb[r]);
    asm("v_cvt_pk_bf16_f32 %0, %1, %2" : "=v"(u0) : "v"(Sb[0]),  "v"(Sb[1]));
    asm("v_cvt_pk_bf16_f32 %0, %1, %2" : "=v"(u1) : "v"(Sb[2]),  "v"(Sb[3]));
    asm("v_cvt_pk_bf16_f32 %0, %1, %2" : "=v"(u2) : "v"(Sb[4]),  "v"(Sb[5]));
    asm("v_cvt_pk_bf16_f32 %0, %1, %2" : "=v"(u3) : "v"(Sb[6]),  "v"(Sb[7]));
    asm("v_cvt_pk_bf16_f32 %0, %1, %2" : "=v"(u4) : "v"(Sb[8]),  "v"(Sb[9]));
    asm("v_cvt_pk_bf16_f32 %0, %1, %2" : "=v"(u5) : "v"(Sb[10]), "v"(Sb[11]));
    asm("v_cvt_pk_bf16_f32 %0, %1, %2" : "=v"(u6) : "v"(Sb[12]), "v"(Sb[13]));
    asm("v_cvt_pk_bf16_f32 %0, %1, %2" : "=v"(u7) : "v"(Sb[14]), "v"(Sb[15]));
    asm("v_permlane32_swap_b32 %0, %1" : "+v"(u0), "+v"(u2));
    asm("v_permlane32_swap_b32 %0, %1" : "+v"(u1), "+v"(u3));
    asm("v_permlane32_swap_b32 %0, %1" : "+v"(u4), "+v"(u6));
    asm("v_permlane32_swap_b32 %0, %1" : "+v"(u5), "+v"(u7));
    {
      uint4 fb0 = make_uint4(u0, u1, u2, u3);
      uint4 fb1 = make_uint4(u4, u5, u6, u7);
      a10 = mfma_bf16(__builtin_bit_cast(bf16x8, fb0), __builtin_bit_cast(bf16x8, g00), a10);
      a11 = mfma_bf16(__builtin_bit_cast(bf16x8, fb0), __builtin_bit_cast(bf16x8, g01), a11);
      a10 = mfma_bf16(__builtin_bit_cast(bf16x8, fb1), __builtin_bit_cast(bf16x8, g10), a10);
      a11 = mfma_bf16(__builtin_bit_cast(bf16x8, fb1), __builtin_bit_cast(bf16x8, g11), a11);
    }

    pA = pAn;
    g00 = n00; g01 = n01; g10 = n10; g11 = n11;
  }

  int mode = flag[0];
  float ga = ldany(gamma, 0, mode);
  float alpha = 1.f / (1.f + __expf(-ga));

  #pragma unroll
  for (int h = 0; h < 2; ++h) {
    __syncthreads();
    {
      f32x16 ac0 = (h == 0) ? a00 : a10;
      f32x16 ac1 = (h == 0) ? a01 : a11;
      #pragma unroll
      for (int r = 0; r < 16; ++r) {
        int qq = (r & 3) + 8 * (r >> 2) + 4 * lh;
        agPart[mq][qq][lr]      = ac0[r];
        agPart[mq][qq][32 + lr] = ac1[r];
      }
    }
    __syncthreads();
    {
      #pragma unroll
      for (int jj = 0; jj < 8; ++jj) {
        int c = mq * 16 + lh * 8 + jj;
        float vsum = agPart[0][lr][c] + agPart[1][lr][c] + agPart[2][lr][c] + agPart[3][lr][c];
        agF[lr][c] = f2bf(vsum);
      }
    }
    __syncthreads();
    {
      f32x16 oacc;
      #pragma unroll
      for (int i = 0; i < 16; ++i) oacc[i] = 0.f;
      #pragma unroll
      for (int ks = 0; ks < 4; ++ks) {
        bf16x8 aw = __builtin_bit_cast(bf16x8, wF[(mq * 4 + ks) * 64 + l]);
        bf16x8 bg = __builtin_bit_cast(bf16x8, *(const uint4*)&agF[lr][ks * 16 + lh * 8]);
        oacc = mfma_bf16(aw, bg, oacc);
      }
      if (mode) {
        float* o0 = (float*)out_base;
        float* o1 = o0 + NX;
        const float* xf = (const float*)x;
        #pragma unroll
        for (int r = 0; r < 16; ++r) {
          int o = mq * 32 + (r & 3) + 8 * (r >> 2) + 4 * lh;
          size_t oi = ((size_t)b * CH + o) * NQ + q0 + h * 32 + lr;
          float ag = oacc[r] + bAllf[96 + o];
          o0[oi] = (1.f - alpha) * xf[oi] + alpha * ag;
          o1[oi] = ag;
        }
      } else {
        ushort* o0 = (ushort*)out_base;
        ushort* o1 = o0 + NX;
        const ushort* xu = (const ushort*)x;
        #pragma unroll
        for (int r = 0; r < 16; ++r) {
          int o = mq * 32 + (r & 3) + 8 * (r >> 2) + 4 * lh;
          size_t oi = ((size_t)b * CH + o) * NQ + q0 + h * 32 + lr;
          float ag = oacc[r] + bAllf[96 + o];
          o0[oi] = f2bf((1.f - alpha) * bf2f(xu[oi]) + alpha * ag);
          o1[oi] = f2bf(ag);
        }
      }
    }
  }
}

extern "C" void kernel_launch(void* const* d_in, const int* in_sizes, int n_in,
                              void* d_out, int out_size, void* d_ws, size_t ws_size,
                              hipStream_t stream) {
  const void* x    = d_in[0];
  const void* wT   = d_in[1];
  const void* bT   = d_in[2];
  const void* wP   = d_in[3];
  const void* bP   = d_in[4];
  const void* wG   = d_in[5];
  const void* bG   = d_in[6];
  const void* wAG  = d_in[7];
  const void* bAG  = d_in[8];
  const void* gmm  = d_in[9];

  char* ws = (char*)d_ws;
  ushort* theta  = (ushort*)(ws + 0);          // 1 MB
  ushort* phi    = (ushort*)(ws + 1048576);    // 256 KB
  ushort* gm     = (ushort*)(ws + 1310720);    // 1 MB  [b][m][64] bf16
  uint4*  gsF    = (uint4*) (ws + 3407872);    // 1 MB  pre-swizzled PV B-frags
  uint4*  wF     = (uint4*) (ws + 4456448);    // 16 KB
  uint4*  wBf    = (uint4*) (ws + 4472832);    // 24 KB k_proj B-frags
  float*  bAllf  = (float*) (ws + 4497408);    // 1 KB
  int*    flag   = (int*)   (ws + 4498432);    // 4 B

  k_prep<<<dim3(11), dim3(256), 0, stream>>>(x, wT, bT, wP, bP, wG, bG, wAG, bAG, flag, bAllf, wF, wBf);
  k_proj<<<dim3(256, 2), dim3(256), 0, stream>>>(x, flag, wBf, bAllf, theta, phi, gm);
  k_denom2<<<dim3(128, 2), dim3(1024), 0, stream>>>(theta, phi, gm, gsF);
  k_attn<<<dim3(256, 2), dim3(256), 0, stream>>>(theta, phi, gsF, wF, bAllf, x, gmm, flag, d_out);
}

// Round 20
// 72.460 us; speedup vs baseline: 1.0977x; 1.0087x over previous
//
#include <hip/hip_runtime.h>

typedef short bf16x8 __attribute__((ext_vector_type(8)));
typedef float f32x16 __attribute__((ext_vector_type(16)));

#define DI __device__ __forceinline__

constexpr int BS = 2, CH = 128;
constexpr int NQ = 16384, NM = 4096;
constexpr size_t NX = (size_t)BS * CH * NQ;   // elements per output tensor

DI float bf2f(ushort u) { unsigned v = ((unsigned)u) << 16; return __builtin_bit_cast(float, v); }
DI ushort f2bf(float f) {
  unsigned u = __builtin_bit_cast(unsigned, f);
  u += 0x7FFFu + ((u >> 16) & 1u);   // RNE
  return (ushort)(u >> 16);
}
DI float ldany(const void* p, size_t i, int f) {
  return f ? ((const float*)p)[i] : bf2f(((const ushort*)p)[i]);
}
DI f32x16 mfma_bf16(bf16x8 a, bf16x8 b, f32x16 c) {
  return __builtin_amdgcn_mfma_f32_32x32x16_bf16(a, b, c, 0, 0, 0);
}
DI float fexp2(float x) { return __builtin_amdgcn_exp2f(x); }   // 1x v_exp_f32

// block-local parallel dtype sniff (first 256 ushorts of x); all blocks agree.
DI int sniff_block(const void* x, int t, int* cnt_sh) {
  const ushort* u = (const ushort*)x;
  if (t == 0) { cnt_sh[0] = 0; cnt_sh[1] = 0; }
  __syncthreads();
  if (t < 256) {
    float v = bf2f(u[t]);
    if (!(fabsf(v) < 1e9f)) atomicAdd(&cnt_sh[0], 1);
    if (((t & 1) == 0) && (u[t] == 0)) atomicAdd(&cnt_sh[1], 1);
  }
  __syncthreads();
  return (cnt_sh[0] >= 8 || cnt_sh[1] >= 100) ? 1 : 0;   // 1 = f32 buffers
}

// ---------------- projections via MFMA (self-contained; block (0,0) publishes
//                  k_attn's wF frags + bAG biases to global) -------------------
// 256 threads = 4 waves = (qhalf) x (khalf); 64 q per block. LDS ~33 KB.
__global__ __launch_bounds__(256) void k_proj(
    const void* __restrict__ x,
    const void* __restrict__ wT, const void* __restrict__ bT,
    const void* __restrict__ wP, const void* __restrict__ bP,
    const void* __restrict__ wG, const void* __restrict__ bG,
    const void* __restrict__ wAG, const void* __restrict__ bAG,
    ushort* __restrict__ theta, ushort* __restrict__ phi, ushort* __restrict__ gm,
    uint4* __restrict__ wFg, float* __restrict__ bagg)
{
  int b = blockIdx.y;
  int qt = blockIdx.x;              // 0..255, 64 q each
  int t = threadIdx.x;
  int w = t >> 6, l = t & 63, lr = l & 31, lh = l >> 5;
  int qhalf = w & 1, khalf = w >> 1;

  __shared__ int cnt_sh[2];
  __shared__ __align__(16) uint4 wBf_sh[24][64];   // 24 KB
  __shared__ float bias_sh[96];
  __shared__ float tile[64][33];

  int f = sniff_block(x, t, cnt_sh);

  for (int idx = t; idx < 1536; idx += 256) {
    int kb = idx / 192, rem = idx % 192;
    int ob = rem >> 6, lane = rem & 63;
    int r = ob * 32 + (lane & 31);
    int c = kb * 16 + (lane >> 5) * 8;
    const void* src; int row;
    if (r < 16)      { src = wT; row = r; }
    else if (r < 32) { src = wP; row = r - 16; }
    else             { src = wG; row = r - 32; }
    union { uint4 v4; ushort s[8]; } o;
    #pragma unroll
    for (int j = 0; j < 8; ++j) o.s[j] = f2bf(ldany(src, (size_t)row * 128 + c + j, f));
    wBf_sh[kb * 3 + ob][lane] = o.v4;
  }
  if (t < 16)       bias_sh[t] = ldany(bT, t, f);
  else if (t < 32)  bias_sh[t] = ldany(bP, t - 16, f);
  else if (t < 96)  bias_sh[t] = ldany(bG, t - 32, f);

  // publish k_attn's tables once (stream-ordered before k_attn)
  if (qt == 0 && b == 0) {
    for (int i = t; i < 1024; i += 256) {
      int lane = i & 63, ks = (i >> 6) & 3, ot = i >> 8;
      size_t src = (size_t)(ot * 32 + (lane & 31)) * 64 + ks * 16 + (lane >> 5) * 8;
      union { uint4 v4; ushort s[8]; } o;
      #pragma unroll
      for (int j = 0; j < 8; ++j) o.s[j] = f2bf(ldany(wAG, src + j, f));
      wFg[i] = o.v4;
    }
    if (t < 128) bagg[t] = ldany(bAG, t, f);
  }
  __syncthreads();

  size_t xbase = (size_t)b * CH * NQ + qt * 64 + qhalf * 32 + lr;

  f32x16 acc0, acc1, acc2;
  #pragma unroll
  for (int i = 0; i < 16; ++i) { acc0[i] = 0.f; acc1[i] = 0.f; acc2[i] = 0.f; }

  #pragma unroll
  for (int kk = 0; kk < 4; ++kk) {
    int kb = khalf * 4 + kk;
    union { uint4 v4; ushort s[8]; } a;
    int cb = kb * 16 + lh * 8;
    if (f) {
      const float* xf = (const float*)x;
      #pragma unroll
      for (int j = 0; j < 8; ++j) a.s[j] = f2bf(xf[xbase + (size_t)(cb + j) * NQ]);
    } else {
      const ushort* xu = (const ushort*)x;
      #pragma unroll
      for (int j = 0; j < 8; ++j) a.s[j] = xu[xbase + (size_t)(cb + j) * NQ];
    }
    bf16x8 aF = __builtin_bit_cast(bf16x8, a.v4);
    uint4 b0 = wBf_sh[kb * 3 + 0][l];
    uint4 b1 = wBf_sh[kb * 3 + 1][l];
    uint4 b2 = wBf_sh[kb * 3 + 2][l];
    acc0 = mfma_bf16(aF, __builtin_bit_cast(bf16x8, b0), acc0);
    acc1 = mfma_bf16(aF, __builtin_bit_cast(bf16x8, b1), acc1);
    acc2 = mfma_bf16(aF, __builtin_bit_cast(bf16x8, b2), acc2);
  }

  constexpr float L2E = 1.4426950408889634f;

  #pragma unroll
  for (int ob = 0; ob < 3; ++ob) {
    f32x16 A = (ob == 0) ? acc0 : ((ob == 1) ? acc1 : acc2);
    __syncthreads();
    if (khalf == 1) {
      #pragma unroll
      for (int r = 0; r < 16; ++r) {
        int qq = (r & 3) + 8 * (r >> 2) + 4 * lh;
        tile[qhalf * 32 + qq][lr] = A[r];
      }
    }
    __syncthreads();
    if (khalf == 0) {
      #pragma unroll
      for (int r = 0; r < 16; ++r) {
        int qq = (r & 3) + 8 * (r >> 2) + 4 * lh;
        tile[qhalf * 32 + qq][lr] += A[r];
      }
    }
    __syncthreads();
    if (ob == 0) {
      if (t < 64) {                      // theta
        union { uint4 v4[2]; ushort s[16]; } th;
        #pragma unroll
        for (int c = 0; c < 16; ++c)
          th.s[c] = f2bf(tanhf(tile[t][c] + bias_sh[c]) * L2E);
        uint4* dst = (uint4*)(theta + ((size_t)b * NQ + qt * 64 + t) * 16);
        dst[0] = th.v4[0]; dst[1] = th.v4[1];
      } else if (t < 128) {              // phi
        int idx = t - 64;
        int m = idx >> 2, c4 = (idx & 3) * 4;
        int h2 = m * 2;
        union { uint2 v2; ushort s[4]; } ph;
        #pragma unroll
        for (int cc = 0; cc < 4; ++cc) {
          int c = 16 + c4 + cc;
          float z = fmaxf(fmaxf(tile[h2][c], tile[h2 + 1][c]),
                          fmaxf(tile[32 + h2][c], tile[32 + h2 + 1][c]));
          ph.s[cc] = f2bf(tanhf(z + bias_sh[c]));
        }
        *(uint2*)(phi + ((size_t)b * NM + qt * 16 + m) * 16 + c4) = ph.v2;
      }
    } else {                             // g
      if (t < 128) {
        int cb = (ob - 1) * 32;
        int m = t >> 3, c4 = (t & 7) * 4;
        int h2 = m * 2;
        union { uint2 v2; ushort s[4]; } gv;
        #pragma unroll
        for (int cc = 0; cc < 4; ++cc) {
          int c = c4 + cc;
          float z = fmaxf(fmaxf(tile[h2][c], tile[h2 + 1][c]),
                          fmaxf(tile[32 + h2][c], tile[32 + h2 + 1][c]));
          gv.s[cc] = f2bf(z + bias_sh[32 + cb + c]);
        }
        *(uint2*)(gm + ((size_t)b * NM + qt * 16 + m) * 64 + cb + c4) = gv.v2;
      }
    }
  }
}

// ---------------- denominator + scale + PV B-frag pack (unchanged champion) ---
__global__ __launch_bounds__(1024, 2) void k_denom2(
    const ushort* __restrict__ theta, const ushort* __restrict__ phi,
    const ushort* __restrict__ gm, uint4* __restrict__ gsF)
{
  int b = blockIdx.y, mb = blockIdx.x;   // 128 chunks of 32 m
  int t = threadIdx.x;
  int w = t >> 6, l = t & 63, lr = l & 31, lh = l >> 5;
  int mbase = mb * 32;

  __shared__ float part[16][33];
  __shared__ float dinv_sh[32];
  __shared__ float tile[32][65];

  bf16x8 pB = __builtin_bit_cast(bf16x8, *(const uint4*)(phi + ((size_t)b * NM + mbase + lr) * 16 + lh * 8));
  const ushort* thb = theta + ((size_t)b * NQ + w * 1024 + lr) * 16 + lh * 8;

  bf16x8 tA1 = __builtin_bit_cast(bf16x8, *(const uint4*)(thb + 512));
  f32x16 S;
  #pragma unroll
  for (int i = 0; i < 16; ++i) S[i] = 0.f;
  S = mfma_bf16(__builtin_bit_cast(bf16x8, *(const uint4*)thb), pB, S);

  float s = 0.f;
  for (int it = 0; it < 32; ++it) {
    bf16x8 tA2 = __builtin_bit_cast(bf16x8, *(const uint4*)(thb + (size_t)((it + 2) & 31) * 512));
    __builtin_amdgcn_sched_barrier(0);
    f32x16 Sn;
    #pragma unroll
    for (int i = 0; i < 16; ++i) Sn[i] = 0.f;
    Sn = mfma_bf16(tA1, pB, Sn);          // next tile's S overlaps this exp block
    #pragma unroll
    for (int r = 0; r < 16; ++r) s += fexp2(S[r]);
    S = Sn; tA1 = tA2;
  }
  s += __shfl_xor(s, 32, 64);
  if (l < 32) part[w][lr] = s;
  __syncthreads();

  if (t < 32) {
    float d = 0.f;
    #pragma unroll
    for (int p = 0; p < 16; ++p) d += part[p][t];
    dinv_sh[t] = 1.f / d;
  }
  __syncthreads();

  if (t < 256) {
    int m_loc = t >> 3, c = (t & 7) * 8;
    union { uint4 v4; ushort s[8]; } v;
    v.v4 = *(const uint4*)(gm + ((size_t)b * NM + mbase + m_loc) * 64 + c);
    float dv = dinv_sh[m_loc];
    #pragma unroll
    for (int j = 0; j < 8; ++j) tile[m_loc][c + j] = bf2f(v.s[j]) * dv;
  }
  __syncthreads();

  if (t < 256) {
    int ms_loc = t >> 7, ct = (t >> 6) & 1, lane = t & 63;
    int col = ct * 32 + (lane & 31);
    int rbase = ms_loc * 16 + (lane >> 5) * 8;
    union { uint4 v4; ushort s[8]; } o;
    #pragma unroll
    for (int j = 0; j < 8; ++j) o.s[j] = f2bf(tile[rbase + j][col]);
    int ms = (mbase >> 4) + ms_loc;
    gsF[(((size_t)b * 256 + ms) * 2 + ct) * 64 + lane] = o.v4;
  }
}

// ---------------- fused attention + output (champion loop + batch-XCD swizzle) -
// idx -> (xcd = idx&7, slot = idx>>3): b = xcd>>2, q0 = ((xcd&3)*64+slot)*64.
// Bijective; each XCD serves ONE batch (R17 counters: FETCH 13.97 -> 11.48 MB).
// LDS stays 38.4 KB (champion); wF/bAG read from global as in champion.
__global__ __launch_bounds__(256, 3) void k_attn(
    const ushort* __restrict__ theta, const ushort* __restrict__ phi,
    const uint4* __restrict__ gsF, const uint4* __restrict__ wF,
    const float* __restrict__ bagg, const void* __restrict__ x,
    const void* __restrict__ gamma, void* __restrict__ out_base)
{
  int idx = blockIdx.x;              // 0..511
  int xcd = idx & 7, slot = idx >> 3;
  int b = xcd >> 2;
  int q0 = ((xcd & 3) * 64 + slot) * 64;
  int t = threadIdx.x;
  int mq = t >> 6, l = t & 63, lr = l & 31, lh = l >> 5;

  __shared__ int cnt_sh[2];
  __shared__ float agPart[4][32][65];
  __shared__ __align__(16) ushort agF[32][80];

  int f = sniff_block(x, t, cnt_sh);

  bf16x8 tB0 = __builtin_bit_cast(bf16x8, *(const uint4*)(theta + ((size_t)b * NQ + q0 + lr) * 16 + lh * 8));
  bf16x8 tB1 = __builtin_bit_cast(bf16x8, *(const uint4*)(theta + ((size_t)b * NQ + q0 + 32 + lr) * 16 + lh * 8));

  const ushort* phb = phi + ((size_t)b * NM + lr) * 16 + lh * 8;
  const uint4* gF = gsF + (size_t)b * 32768;

  f32x16 a00, a01, a10, a11;
  #pragma unroll
  for (int i = 0; i < 16; ++i) { a00[i] = 0.f; a01[i] = 0.f; a10[i] = 0.f; a11[i] = 0.f; }
  f32x16 zero16;
  #pragma unroll
  for (int i = 0; i < 16; ++i) zero16[i] = 0.f;

  size_t gb0 = (size_t)(mq * 2) * 128;
  uint4 g00 = gF[gb0 + l];
  uint4 g01 = gF[gb0 + 64 + l];
  uint4 g10 = gF[gb0 + 128 + l];
  uint4 g11 = gF[gb0 + 192 + l];
  bf16x8 pA = __builtin_bit_cast(bf16x8, *(const uint4*)(phb + (size_t)(mq * 32) * 16));

  for (int it = 0; it < 32; ++it) {
    int it1 = (it + 1) & 31;
    size_t gb = (size_t)(mq * 2 + it1 * 8) * 128;
    uint4 n00 = gF[gb + l];
    uint4 n01 = gF[gb + 64 + l];
    uint4 n10 = gF[gb + 128 + l];
    uint4 n11 = gF[gb + 192 + l];
    bf16x8 pAn = __builtin_bit_cast(bf16x8, *(const uint4*)(phb + (size_t)(mq * 32 + it1 * 128) * 16));
    __builtin_amdgcn_sched_barrier(0);

    f32x16 Sa = mfma_bf16(pA, tB0, zero16);
    f32x16 Sb = mfma_bf16(pA, tB1, zero16);

    uint u0, u1, u2, u3, u4, u5, u6, u7;

    #pragma unroll
    for (int r = 0; r < 16; ++r) Sa[r] = fexp2(Sa[r]);
    asm("v_cvt_pk_bf16_f32 %0, %1, %2" : "=v"(u0) : "v"(Sa[0]),  "v"(Sa[1]));
    asm("v_cvt_pk_bf16_f32 %0, %1, %2" : "=v"(u1) : "v"(Sa[2]),  "v"(Sa[3]));
    asm("v_cvt_pk_bf16_f32 %0, %1, %2" : "=v"(u2) : "v"(Sa[4]),  "v"(Sa[5]));
    asm("v_cvt_pk_bf16_f32 %0, %1, %2" : "=v"(u3) : "v"(Sa[6]),  "v"(Sa[7]));
    asm("v_cvt_pk_bf16_f32 %0, %1, %2" : "=v"(u4) : "v"(Sa[8]),  "v"(Sa[9]));
    asm("v_cvt_pk_bf16_f32 %0, %1, %2" : "=v"(u5) : "v"(Sa[10]), "v"(Sa[11]));
    asm("v_cvt_pk_bf16_f32 %0, %1, %2" : "=v"(u6) : "v"(Sa[12]), "v"(Sa[13]));
    asm("v_cvt_pk_bf16_f32 %0, %1, %2" : "=v"(u7) : "v"(Sa[14]), "v"(Sa[15]));
    asm("v_permlane32_swap_b32 %0, %1" : "+v"(u0), "+v"(u2));
    asm("v_permlane32_swap_b32 %0, %1" : "+v"(u1), "+v"(u3));
    asm("v_permlane32_swap_b32 %0, %1" : "+v"(u4), "+v"(u6));
    asm("v_permlane32_swap_b32 %0, %1" : "+v"(u5), "+v"(u7));
    {
      uint4 fa0 = make_uint4(u0, u1, u2, u3);
      uint4 fa1 = make_uint4(u4, u5, u6, u7);
      a00 = mfma_bf16(__builtin_bit_cast(bf16x8, fa0), __builtin_bit_cast(bf16x8, g00), a00);
      a01 = mfma_bf16(__builtin_bit_cast(bf16x8, fa0), __builtin_bit_cast(bf16x8, g01), a01);
      a00 = mfma_bf16(__builtin_bit_cast(bf16x8, fa1), __builtin_bit_cast(bf16x8, g10), a00);
      a01 = mfma_bf16(__builtin_bit_cast(bf16x8, fa1), __builtin_bit_cast(bf16x8, g11), a01);
    }

    #pragma unroll
    for (int r = 0; r < 16; ++r) Sb[r] = fexp2(Sb[r]);
    asm("v_cvt_pk_bf16_f32 %0, %1, %2" : "=v"(u0) : "v"(Sb[0]),  "v"(Sb[1]));
    asm("v_cvt_pk_bf16_f32 %0, %1, %2" : "=v"(u1) : "v"(Sb[2]),  "v"(Sb[3]));
    asm("v_cvt_pk_bf16_f32 %0, %1, %2" : "=v"(u2) : "v"(Sb[4]),  "v"(Sb[5]));
    asm("v_cvt_pk_bf16_f32 %0, %1, %2" : "=v"(u3) : "v"(Sb[6]),  "v"(Sb[7]));
    asm("v_cvt_pk_bf16_f32 %0, %1, %2" : "=v"(u4) : "v"(Sb[8]),  "v"(Sb[9]));
    asm("v_cvt_pk_bf16_f32 %0, %1, %2" : "=v"(u5) : "v"(Sb[10]), "v"(Sb[11]));
    asm("v_cvt_pk_bf16_f32 %0, %1, %2" : "=v"(u6) : "v"(Sb[12]), "v"(Sb[13]));
    asm("v_cvt_pk_bf16_f32 %0, %1, %2" : "=v"(u7) : "v"(Sb[14]), "v"(Sb[15]));
    asm("v_permlane32_swap_b32 %0, %1" : "+v"(u0), "+v"(u2));
    asm("v_permlane32_swap_b32 %0, %1" : "+v"(u1), "+v"(u3));
    asm("v_permlane32_swap_b32 %0, %1" : "+v"(u4), "+v"(u6));
    asm("v_permlane32_swap_b32 %0, %1" : "+v"(u5), "+v"(u7));
    {
      uint4 fb0 = make_uint4(u0, u1, u2, u3);
      uint4 fb1 = make_uint4(u4, u5, u6, u7);
      a10 = mfma_bf16(__builtin_bit_cast(bf16x8, fb0), __builtin_bit_cast(bf16x8, g00), a10);
      a11 = mfma_bf16(__builtin_bit_cast(bf16x8, fb0), __builtin_bit_cast(bf16x8, g01), a11);
      a10 = mfma_bf16(__builtin_bit_cast(bf16x8, fb1), __builtin_bit_cast(bf16x8, g10), a10);
      a11 = mfma_bf16(__builtin_bit_cast(bf16x8, fb1), __builtin_bit_cast(bf16x8, g11), a11);
    }

    pA = pAn;
    g00 = n00; g01 = n01; g10 = n10; g11 = n11;
  }

  float ga = ldany(gamma, 0, f);
  float alpha = 1.f / (1.f + __expf(-ga));

  #pragma unroll
  for (int h = 0; h < 2; ++h) {
    __syncthreads();
    {
      f32x16 ac0 = (h == 0) ? a00 : a10;
      f32x16 ac1 = (h == 0) ? a01 : a11;
      #pragma unroll
      for (int r = 0; r < 16; ++r) {
        int qq = (r & 3) + 8 * (r >> 2) + 4 * lh;
        agPart[mq][qq][lr]      = ac0[r];
        agPart[mq][qq][32 + lr] = ac1[r];
      }
    }
    __syncthreads();
    {
      #pragma unroll
      for (int jj = 0; jj < 8; ++jj) {
        int c = mq * 16 + lh * 8 + jj;
        float vsum = agPart[0][lr][c] + agPart[1][lr][c] + agPart[2][lr][c] + agPart[3][lr][c];
        agF[lr][c] = f2bf(vsum);
      }
    }
    __syncthreads();
    {
      f32x16 oacc;
      #pragma unroll
      for (int i = 0; i < 16; ++i) oacc[i] = 0.f;
      #pragma unroll
      for (int ks = 0; ks < 4; ++ks) {
        bf16x8 aw = __builtin_bit_cast(bf16x8, wF[(mq * 4 + ks) * 64 + l]);
        bf16x8 bg = __builtin_bit_cast(bf16x8, *(const uint4*)&agF[lr][ks * 16 + lh * 8]);
        oacc = mfma_bf16(aw, bg, oacc);
      }
      if (f) {
        float* o0 = (float*)out_base;
        float* o1 = o0 + NX;
        const float* xf = (const float*)x;
        #pragma unroll
        for (int r = 0; r < 16; ++r) {
          int o = mq * 32 + (r & 3) + 8 * (r >> 2) + 4 * lh;
          size_t oi = ((size_t)b * CH + o) * NQ + q0 + h * 32 + lr;
          float ag = oacc[r] + bagg[o];
          o0[oi] = (1.f - alpha) * xf[oi] + alpha * ag;
          o1[oi] = ag;
        }
      } else {
        ushort* o0 = (ushort*)out_base;
        ushort* o1 = o0 + NX;
        const ushort* xu = (const ushort*)x;
        #pragma unroll
        for (int r = 0; r < 16; ++r) {
          int o = mq * 32 + (r & 3) + 8 * (r >> 2) + 4 * lh;
          size_t oi = ((size_t)b * CH + o) * NQ + q0 + h * 32 + lr;
          float ag = oacc[r] + bagg[o];
          o0[oi] = f2bf((1.f - alpha) * bf2f(xu[oi]) + alpha * ag);
          o1[oi] = f2bf(ag);
        }
      }
    }
  }
}

extern "C" void kernel_launch(void* const* d_in, const int* in_sizes, int n_in,
                              void* d_out, int out_size, void* d_ws, size_t ws_size,
                              hipStream_t stream) {
  const void* x    = d_in[0];
  const void* wT   = d_in[1];
  const void* bT   = d_in[2];
  const void* wP   = d_in[3];
  const void* bP   = d_in[4];
  const void* wG   = d_in[5];
  const void* bG   = d_in[6];
  const void* wAG  = d_in[7];
  const void* bAG  = d_in[8];
  const void* gmm  = d_in[9];

  char* ws = (char*)d_ws;
  ushort* theta  = (ushort*)(ws + 0);          // 1 MB
  ushort* phi    = (ushort*)(ws + 1048576);    // 256 KB
  ushort* gm     = (ushort*)(ws + 1310720);    // 1 MB  [b][m][64] bf16
  uint4*  gsF    = (uint4*) (ws + 3407872);    // 1 MB  pre-swizzled PV B-frags
  uint4*  wFg    = (uint4*) (ws + 4456448);    // 16 KB epilogue A-frags
  float*  bagg   = (float*) (ws + 4472832);    // 512 B bAG biases

  k_proj<<<dim3(256, 2), dim3(256), 0, stream>>>(x, wT, bT, wP, bP, wG, bG, wAG, bAG,
                                                 theta, phi, gm, wFg, bagg);
  k_denom2<<<dim3(128, 2), dim3(1024), 0, stream>>>(theta, phi, gm, gsF);
  k_attn<<<dim3(512), dim3(256), 0, stream>>>(theta, phi, gsF, wFg, bagg, x, gmm, d_out);
}

// Round 21
// 72.235 us; speedup vs baseline: 1.1011x; 1.0031x over previous
//
#include <hip/hip_runtime.h>

typedef short bf16x8 __attribute__((ext_vector_type(8)));
typedef float f32x16 __attribute__((ext_vector_type(16)));

#define DI __device__ __forceinline__

constexpr int BS = 2, CH = 128;
constexpr int NQ = 16384, NM = 4096;
constexpr size_t NX = (size_t)BS * CH * NQ;   // elements per output tensor

DI float bf2f(ushort u) { unsigned v = ((unsigned)u) << 16; return __builtin_bit_cast(float, v); }
DI ushort f2bf(float f) {
  unsigned u = __builtin_bit_cast(unsigned, f);
  u += 0x7FFFu + ((u >> 16) & 1u);   // RNE
  return (ushort)(u >> 16);
}
DI float ldany(const void* p, size_t i, int f) {
  return f ? ((const float*)p)[i] : bf2f(((const ushort*)p)[i]);
}
DI f32x16 mfma_bf16(bf16x8 a, bf16x8 b, f32x16 c) {
  return __builtin_amdgcn_mfma_f32_32x32x16_bf16(a, b, c, 0, 0, 0);
}
DI float fexp2(float x) { return __builtin_amdgcn_exp2f(x); }   // 1x v_exp_f32

// block-local parallel dtype sniff (first 256 ushorts of x); all blocks agree.
DI int sniff_block(const void* x, int t, int* cnt_sh) {
  const ushort* u = (const ushort*)x;
  if (t == 0) { cnt_sh[0] = 0; cnt_sh[1] = 0; }
  __syncthreads();
  if (t < 256) {
    float v = bf2f(u[t]);
    if (!(fabsf(v) < 1e9f)) atomicAdd(&cnt_sh[0], 1);
    if (((t & 1) == 0) && (u[t] == 0)) atomicAdd(&cnt_sh[1], 1);
  }
  __syncthreads();
  return (cnt_sh[0] >= 8 || cnt_sh[1] >= 100) ? 1 : 0;   // 1 = f32 buffers
}

// ---------------- projections via MFMA (self-contained; emits g directly as
//                  unscaled PV B-frags gFu; block (0,0) publishes wF/bAG) ------
// 256 threads = 4 waves = (qhalf) x (khalf); 64 q per block.
__global__ __launch_bounds__(256) void k_proj(
    const void* __restrict__ x,
    const void* __restrict__ wT, const void* __restrict__ bT,
    const void* __restrict__ wP, const void* __restrict__ bP,
    const void* __restrict__ wG, const void* __restrict__ bG,
    const void* __restrict__ wAG, const void* __restrict__ bAG,
    ushort* __restrict__ theta, ushort* __restrict__ phi,
    uint4* __restrict__ gFu, uint4* __restrict__ wFg, float* __restrict__ bagg)
{
  int b = blockIdx.y;
  int qt = blockIdx.x;              // 0..255, 64 q each (one 16-m frag group)
  int t = threadIdx.x;
  int w = t >> 6, l = t & 63, lr = l & 31, lh = l >> 5;
  int qhalf = w & 1, khalf = w >> 1;

  __shared__ int cnt_sh[2];
  __shared__ __align__(16) uint4 wBf_sh[24][64];   // 24 KB
  __shared__ float bias_sh[96];
  __shared__ float tile[64][33];
  __shared__ float gpool[16][65];                  // pooled g (pre-scale), f32

  int f = sniff_block(x, t, cnt_sh);

  for (int idx = t; idx < 1536; idx += 256) {
    int kb = idx / 192, rem = idx % 192;
    int ob = rem >> 6, lane = rem & 63;
    int r = ob * 32 + (lane & 31);
    int c = kb * 16 + (lane >> 5) * 8;
    const void* src; int row;
    if (r < 16)      { src = wT; row = r; }
    else if (r < 32) { src = wP; row = r - 16; }
    else             { src = wG; row = r - 32; }
    union { uint4 v4; ushort s[8]; } o;
    #pragma unroll
    for (int j = 0; j < 8; ++j) o.s[j] = f2bf(ldany(src, (size_t)row * 128 + c + j, f));
    wBf_sh[kb * 3 + ob][lane] = o.v4;
  }
  if (t < 16)       bias_sh[t] = ldany(bT, t, f);
  else if (t < 32)  bias_sh[t] = ldany(bP, t - 16, f);
  else if (t < 96)  bias_sh[t] = ldany(bG, t - 32, f);

  // publish k_attn's tables once (stream-ordered before k_attn)
  if (qt == 0 && b == 0) {
    for (int i = t; i < 1024; i += 256) {
      int lane = i & 63, ks = (i >> 6) & 3, ot = i >> 8;
      size_t src = (size_t)(ot * 32 + (lane & 31)) * 64 + ks * 16 + (lane >> 5) * 8;
      union { uint4 v4; ushort s[8]; } o;
      #pragma unroll
      for (int j = 0; j < 8; ++j) o.s[j] = f2bf(ldany(wAG, src + j, f));
      wFg[i] = o.v4;
    }
    if (t < 128) bagg[t] = ldany(bAG, t, f);
  }
  __syncthreads();

  size_t xbase = (size_t)b * CH * NQ + qt * 64 + qhalf * 32 + lr;

  f32x16 acc0, acc1, acc2;
  #pragma unroll
  for (int i = 0; i < 16; ++i) { acc0[i] = 0.f; acc1[i] = 0.f; acc2[i] = 0.f; }

  #pragma unroll
  for (int kk = 0; kk < 4; ++kk) {
    int kb = khalf * 4 + kk;
    union { uint4 v4; ushort s[8]; } a;
    int cb = kb * 16 + lh * 8;
    if (f) {
      const float* xf = (const float*)x;
      #pragma unroll
      for (int j = 0; j < 8; ++j) a.s[j] = f2bf(xf[xbase + (size_t)(cb + j) * NQ]);
    } else {
      const ushort* xu = (const ushort*)x;
      #pragma unroll
      for (int j = 0; j < 8; ++j) a.s[j] = xu[xbase + (size_t)(cb + j) * NQ];
    }
    bf16x8 aF = __builtin_bit_cast(bf16x8, a.v4);
    uint4 b0 = wBf_sh[kb * 3 + 0][l];
    uint4 b1 = wBf_sh[kb * 3 + 1][l];
    uint4 b2 = wBf_sh[kb * 3 + 2][l];
    acc0 = mfma_bf16(aF, __builtin_bit_cast(bf16x8, b0), acc0);
    acc1 = mfma_bf16(aF, __builtin_bit_cast(bf16x8, b1), acc1);
    acc2 = mfma_bf16(aF, __builtin_bit_cast(bf16x8, b2), acc2);
  }

  constexpr float L2E = 1.4426950408889634f;

  #pragma unroll
  for (int ob = 0; ob < 3; ++ob) {
    f32x16 A = (ob == 0) ? acc0 : ((ob == 1) ? acc1 : acc2);
    __syncthreads();
    if (khalf == 1) {
      #pragma unroll
      for (int r = 0; r < 16; ++r) {
        int qq = (r & 3) + 8 * (r >> 2) + 4 * lh;
        tile[qhalf * 32 + qq][lr] = A[r];
      }
    }
    __syncthreads();
    if (khalf == 0) {
      #pragma unroll
      for (int r = 0; r < 16; ++r) {
        int qq = (r & 3) + 8 * (r >> 2) + 4 * lh;
        tile[qhalf * 32 + qq][lr] += A[r];
      }
    }
    __syncthreads();
    if (ob == 0) {
      if (t < 64) {                      // theta
        union { uint4 v4[2]; ushort s[16]; } th;
        #pragma unroll
        for (int c = 0; c < 16; ++c)
          th.s[c] = f2bf(tanhf(tile[t][c] + bias_sh[c]) * L2E);
        uint4* dst = (uint4*)(theta + ((size_t)b * NQ + qt * 64 + t) * 16);
        dst[0] = th.v4[0]; dst[1] = th.v4[1];
      } else if (t < 128) {              // phi
        int idx = t - 64;
        int m = idx >> 2, c4 = (idx & 3) * 4;
        int h2 = m * 2;
        union { uint2 v2; ushort s[4]; } ph;
        #pragma unroll
        for (int cc = 0; cc < 4; ++cc) {
          int c = 16 + c4 + cc;
          float z = fmaxf(fmaxf(tile[h2][c], tile[h2 + 1][c]),
                          fmaxf(tile[32 + h2][c], tile[32 + h2 + 1][c]));
          ph.s[cc] = f2bf(tanhf(z + bias_sh[c]));
        }
        *(uint2*)(phi + ((size_t)b * NM + qt * 16 + m) * 16 + c4) = ph.v2;
      }
    } else {                             // g -> pooled f32 staging (both halves)
      if (t < 128) {
        int cb = (ob - 1) * 32;
        int m = t >> 3, c4 = (t & 7) * 4;
        int h2 = m * 2;
        #pragma unroll
        for (int cc = 0; cc < 4; ++cc) {
          int c = c4 + cc;
          float z = fmaxf(fmaxf(tile[h2][c], tile[h2 + 1][c]),
                          fmaxf(tile[32 + h2][c], tile[32 + h2 + 1][c]));
          gpool[m][cb + c] = z + bias_sh[32 + cb + c];
        }
      }
    }
  }
  __syncthreads();

  // frag-pack: gFu[((b*256+qt)*2+ct)*64+lane], j-th bf16 = pooled[(lane>>5)*8+j][ct*32+(lane&31)]
  if (t < 128) {
    int ct = t >> 6, lane = t & 63;
    int rbase = (lane >> 5) * 8;
    int col = ct * 32 + (lane & 31);
    union { uint4 v4; ushort s[8]; } o;
    #pragma unroll
    for (int j = 0; j < 8; ++j) o.s[j] = f2bf(gpool[rbase + j][col]);
    gFu[(((size_t)b * 256 + qt) * 2 + ct) * 64 + lane] = o.v4;
  }
}

// ---------------- denominator + scale (frag-direct) ----------------
// Grid 256 flat, batch-XCD swizzle: xcd = idx&7 -> b = xcd>>2,
// mb = (xcd&3)*32 + (idx>>3). Each XCD serves ONE batch's theta stream.
// Post-loop: read gFu frags, scale per-m by dinv, write gsF (no transpose).
__global__ __launch_bounds__(1024, 2) void k_denom2(
    const ushort* __restrict__ theta, const ushort* __restrict__ phi,
    const uint4* __restrict__ gFu, uint4* __restrict__ gsF)
{
  int idx = blockIdx.x;              // 0..255
  int xcd = idx & 7;
  int b = xcd >> 2;
  int mb = (xcd & 3) * 32 + (idx >> 3);   // 0..127
  int t = threadIdx.x;
  int w = t >> 6, l = t & 63, lr = l & 31, lh = l >> 5;
  int mbase = mb * 32;

  __shared__ float part[16][33];
  __shared__ float dinv_sh[32];

  bf16x8 pB = __builtin_bit_cast(bf16x8, *(const uint4*)(phi + ((size_t)b * NM + mbase + lr) * 16 + lh * 8));
  const ushort* thb = theta + ((size_t)b * NQ + w * 1024 + lr) * 16 + lh * 8;

  bf16x8 tA1 = __builtin_bit_cast(bf16x8, *(const uint4*)(thb + 512));
  f32x16 S;
  #pragma unroll
  for (int i = 0; i < 16; ++i) S[i] = 0.f;
  S = mfma_bf16(__builtin_bit_cast(bf16x8, *(const uint4*)thb), pB, S);

  float s = 0.f;
  for (int it = 0; it < 32; ++it) {
    bf16x8 tA2 = __builtin_bit_cast(bf16x8, *(const uint4*)(thb + (size_t)((it + 2) & 31) * 512));
    __builtin_amdgcn_sched_barrier(0);
    f32x16 Sn;
    #pragma unroll
    for (int i = 0; i < 16; ++i) Sn[i] = 0.f;
    Sn = mfma_bf16(tA1, pB, Sn);          // next tile's S overlaps this exp block
    #pragma unroll
    for (int r = 0; r < 16; ++r) s += fexp2(S[r]);
    S = Sn; tA1 = tA2;
  }
  s += __shfl_xor(s, 32, 64);
  if (l < 32) part[w][lr] = s;
  __syncthreads();

  if (t < 32) {
    float d = 0.f;
    #pragma unroll
    for (int p = 0; p < 16; ++p) d += part[p][t];
    dinv_sh[t] = 1.f / d;
  }
  __syncthreads();

  if (t < 256) {
    int ms_loc = t >> 7, ct = (t >> 6) & 1, lane = t & 63;
    size_t fi = (((size_t)b * 256 + (mbase >> 4) + ms_loc) * 2 + ct) * 64 + lane;
    union { uint4 v4; ushort s[8]; } v;
    v.v4 = gFu[fi];
    int mloc0 = ms_loc * 16 + (lane >> 5) * 8;
    #pragma unroll
    for (int j = 0; j < 8; ++j) v.s[j] = f2bf(bf2f(v.s[j]) * dinv_sh[mloc0 + j]);
    gsF[fi] = v.v4;
  }
}

// ---------------- fused attention + output (R20 champion, unchanged) ----------
__global__ __launch_bounds__(256, 3) void k_attn(
    const ushort* __restrict__ theta, const ushort* __restrict__ phi,
    const uint4* __restrict__ gsF, const uint4* __restrict__ wF,
    const float* __restrict__ bagg, const void* __restrict__ x,
    const void* __restrict__ gamma, void* __restrict__ out_base)
{
  int idx = blockIdx.x;              // 0..511
  int xcd = idx & 7, slot = idx >> 3;
  int b = xcd >> 2;
  int q0 = ((xcd & 3) * 64 + slot) * 64;
  int t = threadIdx.x;
  int mq = t >> 6, l = t & 63, lr = l & 31, lh = l >> 5;

  __shared__ int cnt_sh[2];
  __shared__ float agPart[4][32][65];
  __shared__ __align__(16) ushort agF[32][80];

  int f = sniff_block(x, t, cnt_sh);

  bf16x8 tB0 = __builtin_bit_cast(bf16x8, *(const uint4*)(theta + ((size_t)b * NQ + q0 + lr) * 16 + lh * 8));
  bf16x8 tB1 = __builtin_bit_cast(bf16x8, *(const uint4*)(theta + ((size_t)b * NQ + q0 + 32 + lr) * 16 + lh * 8));

  const ushort* phb = phi + ((size_t)b * NM + lr) * 16 + lh * 8;
  const uint4* gF = gsF + (size_t)b * 32768;

  f32x16 a00, a01, a10, a11;
  #pragma unroll
  for (int i = 0; i < 16; ++i) { a00[i] = 0.f; a01[i] = 0.f; a10[i] = 0.f; a11[i] = 0.f; }
  f32x16 zero16;
  #pragma unroll
  for (int i = 0; i < 16; ++i) zero16[i] = 0.f;

  size_t gb0 = (size_t)(mq * 2) * 128;
  uint4 g00 = gF[gb0 + l];
  uint4 g01 = gF[gb0 + 64 + l];
  uint4 g10 = gF[gb0 + 128 + l];
  uint4 g11 = gF[gb0 + 192 + l];
  bf16x8 pA = __builtin_bit_cast(bf16x8, *(const uint4*)(phb + (size_t)(mq * 32) * 16));

  for (int it = 0; it < 32; ++it) {
    int it1 = (it + 1) & 31;
    size_t gb = (size_t)(mq * 2 + it1 * 8) * 128;
    uint4 n00 = gF[gb + l];
    uint4 n01 = gF[gb + 64 + l];
    uint4 n10 = gF[gb + 128 + l];
    uint4 n11 = gF[gb + 192 + l];
    bf16x8 pAn = __builtin_bit_cast(bf16x8, *(const uint4*)(phb + (size_t)(mq * 32 + it1 * 128) * 16));
    __builtin_amdgcn_sched_barrier(0);

    f32x16 Sa = mfma_bf16(pA, tB0, zero16);
    f32x16 Sb = mfma_bf16(pA, tB1, zero16);

    uint u0, u1, u2, u3, u4, u5, u6, u7;

    #pragma unroll
    for (int r = 0; r < 16; ++r) Sa[r] = fexp2(Sa[r]);
    asm("v_cvt_pk_bf16_f32 %0, %1, %2" : "=v"(u0) : "v"(Sa[0]),  "v"(Sa[1]));
    asm("v_cvt_pk_bf16_f32 %0, %1, %2" : "=v"(u1) : "v"(Sa[2]),  "v"(Sa[3]));
    asm("v_cvt_pk_bf16_f32 %0, %1, %2" : "=v"(u2) : "v"(Sa[4]),  "v"(Sa[5]));
    asm("v_cvt_pk_bf16_f32 %0, %1, %2" : "=v"(u3) : "v"(Sa[6]),  "v"(Sa[7]));
    asm("v_cvt_pk_bf16_f32 %0, %1, %2" : "=v"(u4) : "v"(Sa[8]),  "v"(Sa[9]));
    asm("v_cvt_pk_bf16_f32 %0, %1, %2" : "=v"(u5) : "v"(Sa[10]), "v"(Sa[11]));
    asm("v_cvt_pk_bf16_f32 %0, %1, %2" : "=v"(u6) : "v"(Sa[12]), "v"(Sa[13]));
    asm("v_cvt_pk_bf16_f32 %0, %1, %2" : "=v"(u7) : "v"(Sa[14]), "v"(Sa[15]));
    asm("v_permlane32_swap_b32 %0, %1" : "+v"(u0), "+v"(u2));
    asm("v_permlane32_swap_b32 %0, %1" : "+v"(u1), "+v"(u3));
    asm("v_permlane32_swap_b32 %0, %1" : "+v"(u4), "+v"(u6));
    asm("v_permlane32_swap_b32 %0, %1" : "+v"(u5), "+v"(u7));
    {
      uint4 fa0 = make_uint4(u0, u1, u2, u3);
      uint4 fa1 = make_uint4(u4, u5, u6, u7);
      a00 = mfma_bf16(__builtin_bit_cast(bf16x8, fa0), __builtin_bit_cast(bf16x8, g00), a00);
      a01 = mfma_bf16(__builtin_bit_cast(bf16x8, fa0), __builtin_bit_cast(bf16x8, g01), a01);
      a00 = mfma_bf16(__builtin_bit_cast(bf16x8, fa1), __builtin_bit_cast(bf16x8, g10), a00);
      a01 = mfma_bf16(__builtin_bit_cast(bf16x8, fa1), __builtin_bit_cast(bf16x8, g11), a01);
    }

    #pragma unroll
    for (int r = 0; r < 16; ++r) Sb[r] = fexp2(Sb[r]);
    asm("v_cvt_pk_bf16_f32 %0, %1, %2" : "=v"(u0) : "v"(Sb[0]),  "v"(Sb[1]));
    asm("v_cvt_pk_bf16_f32 %0, %1, %2" : "=v"(u1) : "v"(Sb[2]),  "v"(Sb[3]));
    asm("v_cvt_pk_bf16_f32 %0, %1, %2" : "=v"(u2) : "v"(Sb[4]),  "v"(Sb[5]));
    asm("v_cvt_pk_bf16_f32 %0, %1, %2" : "=v"(u3) : "v"(Sb[6]),  "v"(Sb[7]));
    asm("v_cvt_pk_bf16_f32 %0, %1, %2" : "=v"(u4) : "v"(Sb[8]),  "v"(Sb[9]));
    asm("v_cvt_pk_bf16_f32 %0, %1, %2" : "=v"(u5) : "v"(Sb[10]), "v"(Sb[11]));
    asm("v_cvt_pk_bf16_f32 %0, %1, %2" : "=v"(u6) : "v"(Sb[12]), "v"(Sb[13]));
    asm("v_cvt_pk_bf16_f32 %0, %1, %2" : "=v"(u7) : "v"(Sb[14]), "v"(Sb[15]));
    asm("v_permlane32_swap_b32 %0, %1" : "+v"(u0), "+v"(u2));
    asm("v_permlane32_swap_b32 %0, %1" : "+v"(u1), "+v"(u3));
    asm("v_permlane32_swap_b32 %0, %1" : "+v"(u4), "+v"(u6));
    asm("v_permlane32_swap_b32 %0, %1" : "+v"(u5), "+v"(u7));
    {
      uint4 fb0 = make_uint4(u0, u1, u2, u3);
      uint4 fb1 = make_uint4(u4, u5, u6, u7);
      a10 = mfma_bf16(__builtin_bit_cast(bf16x8, fb0), __builtin_bit_cast(bf16x8, g00), a10);
      a11 = mfma_bf16(__builtin_bit_cast(bf16x8, fb0), __builtin_bit_cast(bf16x8, g01), a11);
      a10 = mfma_bf16(__builtin_bit_cast(bf16x8, fb1), __builtin_bit_cast(bf16x8, g10), a10);
      a11 = mfma_bf16(__builtin_bit_cast(bf16x8, fb1), __builtin_bit_cast(bf16x8, g11), a11);
    }

    pA = pAn;
    g00 = n00; g01 = n01; g10 = n10; g11 = n11;
  }

  float ga = ldany(gamma, 0, f);
  float alpha = 1.f / (1.f + __expf(-ga));

  #pragma unroll
  for (int h = 0; h < 2; ++h) {
    __syncthreads();
    {
      f32x16 ac0 = (h == 0) ? a00 : a10;
      f32x16 ac1 = (h == 0) ? a01 : a11;
      #pragma unroll
      for (int r = 0; r < 16; ++r) {
        int qq = (r & 3) + 8 * (r >> 2) + 4 * lh;
        agPart[mq][qq][lr]      = ac0[r];
        agPart[mq][qq][32 + lr] = ac1[r];
      }
    }
    __syncthreads();
    {
      #pragma unroll
      for (int jj = 0; jj < 8; ++jj) {
        int c = mq * 16 + lh * 8 + jj;
        float vsum = agPart[0][lr][c] + agPart[1][lr][c] + agPart[2][lr][c] + agPart[3][lr][c];
        agF[lr][c] = f2bf(vsum);
      }
    }
    __syncthreads();
    {
      f32x16 oacc;
      #pragma unroll
      for (int i = 0; i < 16; ++i) oacc[i] = 0.f;
      #pragma unroll
      for (int ks = 0; ks < 4; ++ks) {
        bf16x8 aw = __builtin_bit_cast(bf16x8, wF[(mq * 4 + ks) * 64 + l]);
        bf16x8 bg = __builtin_bit_cast(bf16x8, *(const uint4*)&agF[lr][ks * 16 + lh * 8]);
        oacc = mfma_bf16(aw, bg, oacc);
      }
      if (f) {
        float* o0 = (float*)out_base;
        float* o1 = o0 + NX;
        const float* xf = (const float*)x;
        #pragma unroll
        for (int r = 0; r < 16; ++r) {
          int o = mq * 32 + (r & 3) + 8 * (r >> 2) + 4 * lh;
          size_t oi = ((size_t)b * CH + o) * NQ + q0 + h * 32 + lr;
          float ag = oacc[r] + bagg[o];
          o0[oi] = (1.f - alpha) * xf[oi] + alpha * ag;
          o1[oi] = ag;
        }
      } else {
        ushort* o0 = (ushort*)out_base;
        ushort* o1 = o0 + NX;
        const ushort* xu = (const ushort*)x;
        #pragma unroll
        for (int r = 0; r < 16; ++r) {
          int o = mq * 32 + (r & 3) + 8 * (r >> 2) + 4 * lh;
          size_t oi = ((size_t)b * CH + o) * NQ + q0 + h * 32 + lr;
          float ag = oacc[r] + bagg[o];
          o0[oi] = f2bf((1.f - alpha) * bf2f(xu[oi]) + alpha * ag);
          o1[oi] = f2bf(ag);
        }
      }
    }
  }
}

extern "C" void kernel_launch(void* const* d_in, const int* in_sizes, int n_in,
                              void* d_out, int out_size, void* d_ws, size_t ws_size,
                              hipStream_t stream) {
  const void* x    = d_in[0];
  const void* wT   = d_in[1];
  const void* bT   = d_in[2];
  const void* wP   = d_in[3];
  const void* bP   = d_in[4];
  const void* wG   = d_in[5];
  const void* bG   = d_in[6];
  const void* wAG  = d_in[7];
  const void* bAG  = d_in[8];
  const void* gmm  = d_in[9];

  char* ws = (char*)d_ws;
  ushort* theta  = (ushort*)(ws + 0);          // 1 MB
  ushort* phi    = (ushort*)(ws + 1048576);    // 256 KB
  uint4*  gFu    = (uint4*) (ws + 1310720);    // 1 MB unscaled PV B-frags
  uint4*  gsF    = (uint4*) (ws + 3407872);    // 1 MB scaled PV B-frags
  uint4*  wFg    = (uint4*) (ws + 4456448);    // 16 KB epilogue A-frags
  float*  bagg   = (float*) (ws + 4472832);    // 512 B bAG biases

  k_proj<<<dim3(256, 2), dim3(256), 0, stream>>>(x, wT, bT, wP, bP, wG, bG, wAG, bAG,
                                                 theta, phi, gFu, wFg, bagg);
  k_denom2<<<dim3(256), dim3(1024), 0, stream>>>(theta, phi, gFu, gsF);
  k_attn<<<dim3(512), dim3(256), 0, stream>>>(theta, phi, gsF, wFg, bagg, x, gmm, d_out);
}

// Round 22
// 72.050 us; speedup vs baseline: 1.1039x; 1.0026x over previous
//
#include <hip/hip_runtime.h>

typedef short bf16x8 __attribute__((ext_vector_type(8)));
typedef float f32x16 __attribute__((ext_vector_type(16)));

#define DI __device__ __forceinline__

constexpr int BS = 2, CH = 128;
constexpr int NQ = 16384, NM = 4096;
constexpr size_t NX = (size_t)BS * CH * NQ;   // elements per output tensor

DI float bf2f(ushort u) { unsigned v = ((unsigned)u) << 16; return __builtin_bit_cast(float, v); }
DI ushort f2bf(float f) {
  unsigned u = __builtin_bit_cast(unsigned, f);
  u += 0x7FFFu + ((u >> 16) & 1u);   // RNE
  return (ushort)(u >> 16);
}
DI float ldany(const void* p, size_t i, int f) {
  return f ? ((const float*)p)[i] : bf2f(((const ushort*)p)[i]);
}
DI f32x16 mfma_bf16(bf16x8 a, bf16x8 b, f32x16 c) {
  return __builtin_amdgcn_mfma_f32_32x32x16_bf16(a, b, c, 0, 0, 0);
}
DI float fexp2(float x) { return __builtin_amdgcn_exp2f(x); }   // 1x v_exp_f32

// block-local parallel dtype sniff (first 256 ushorts of x); all blocks agree.
DI int sniff_block(const void* x, int t, int* cnt_sh) {
  const ushort* u = (const ushort*)x;
  if (t == 0) { cnt_sh[0] = 0; cnt_sh[1] = 0; }
  __syncthreads();
  if (t < 256) {
    float v = bf2f(u[t]);
    if (!(fabsf(v) < 1e9f)) atomicAdd(&cnt_sh[0], 1);
    if (((t & 1) == 0) && (u[t] == 0)) atomicAdd(&cnt_sh[1], 1);
  }
  __syncthreads();
  return (cnt_sh[0] >= 8 || cnt_sh[1] >= 100) ? 1 : 0;   // 1 = f32 buffers
}

// ---------------- projections via MFMA (self-contained; emits g directly as
//                  unscaled PV B-frags gFu; block (0,0) publishes wF/bAG) ------
// 256 threads = 4 waves = (qhalf) x (khalf); 64 q per block.
__global__ __launch_bounds__(256) void k_proj(
    const void* __restrict__ x,
    const void* __restrict__ wT, const void* __restrict__ bT,
    const void* __restrict__ wP, const void* __restrict__ bP,
    const void* __restrict__ wG, const void* __restrict__ bG,
    const void* __restrict__ wAG, const void* __restrict__ bAG,
    ushort* __restrict__ theta, ushort* __restrict__ phi,
    uint4* __restrict__ gFu, uint4* __restrict__ wFg, float* __restrict__ bagg)
{
  int b = blockIdx.y;
  int qt = blockIdx.x;              // 0..255, 64 q each (one 16-m frag group)
  int t = threadIdx.x;
  int w = t >> 6, l = t & 63, lr = l & 31, lh = l >> 5;
  int qhalf = w & 1, khalf = w >> 1;

  __shared__ int cnt_sh[2];
  __shared__ __align__(16) uint4 wBf_sh[24][64];   // 24 KB
  __shared__ float bias_sh[96];
  __shared__ float tile[64][33];
  __shared__ float gpool[16][65];                  // pooled g (pre-scale), f32

  int f = sniff_block(x, t, cnt_sh);

  for (int idx = t; idx < 1536; idx += 256) {
    int kb = idx / 192, rem = idx % 192;
    int ob = rem >> 6, lane = rem & 63;
    int r = ob * 32 + (lane & 31);
    int c = kb * 16 + (lane >> 5) * 8;
    const void* src; int row;
    if (r < 16)      { src = wT; row = r; }
    else if (r < 32) { src = wP; row = r - 16; }
    else             { src = wG; row = r - 32; }
    union { uint4 v4; ushort s[8]; } o;
    #pragma unroll
    for (int j = 0; j < 8; ++j) o.s[j] = f2bf(ldany(src, (size_t)row * 128 + c + j, f));
    wBf_sh[kb * 3 + ob][lane] = o.v4;
  }
  if (t < 16)       bias_sh[t] = ldany(bT, t, f);
  else if (t < 32)  bias_sh[t] = ldany(bP, t - 16, f);
  else if (t < 96)  bias_sh[t] = ldany(bG, t - 32, f);

  // publish k_attn's tables once (stream-ordered before k_attn)
  if (qt == 0 && b == 0) {
    for (int i = t; i < 1024; i += 256) {
      int lane = i & 63, ks = (i >> 6) & 3, ot = i >> 8;
      size_t src = (size_t)(ot * 32 + (lane & 31)) * 64 + ks * 16 + (lane >> 5) * 8;
      union { uint4 v4; ushort s[8]; } o;
      #pragma unroll
      for (int j = 0; j < 8; ++j) o.s[j] = f2bf(ldany(wAG, src + j, f));
      wFg[i] = o.v4;
    }
    if (t < 128) bagg[t] = ldany(bAG, t, f);
  }
  __syncthreads();

  size_t xbase = (size_t)b * CH * NQ + qt * 64 + qhalf * 32 + lr;

  f32x16 acc0, acc1, acc2;
  #pragma unroll
  for (int i = 0; i < 16; ++i) { acc0[i] = 0.f; acc1[i] = 0.f; acc2[i] = 0.f; }

  #pragma unroll
  for (int kk = 0; kk < 4; ++kk) {
    int kb = khalf * 4 + kk;
    union { uint4 v4; ushort s[8]; } a;
    int cb = kb * 16 + lh * 8;
    if (f) {
      const float* xf = (const float*)x;
      #pragma unroll
      for (int j = 0; j < 8; ++j) a.s[j] = f2bf(xf[xbase + (size_t)(cb + j) * NQ]);
    } else {
      const ushort* xu = (const ushort*)x;
      #pragma unroll
      for (int j = 0; j < 8; ++j) a.s[j] = xu[xbase + (size_t)(cb + j) * NQ];
    }
    bf16x8 aF = __builtin_bit_cast(bf16x8, a.v4);
    uint4 b0 = wBf_sh[kb * 3 + 0][l];
    uint4 b1 = wBf_sh[kb * 3 + 1][l];
    uint4 b2 = wBf_sh[kb * 3 + 2][l];
    acc0 = mfma_bf16(aF, __builtin_bit_cast(bf16x8, b0), acc0);
    acc1 = mfma_bf16(aF, __builtin_bit_cast(bf16x8, b1), acc1);
    acc2 = mfma_bf16(aF, __builtin_bit_cast(bf16x8, b2), acc2);
  }

  constexpr float L2E = 1.4426950408889634f;

  #pragma unroll
  for (int ob = 0; ob < 3; ++ob) {
    f32x16 A = (ob == 0) ? acc0 : ((ob == 1) ? acc1 : acc2);
    __syncthreads();
    if (khalf == 1) {
      #pragma unroll
      for (int r = 0; r < 16; ++r) {
        int qq = (r & 3) + 8 * (r >> 2) + 4 * lh;
        tile[qhalf * 32 + qq][lr] = A[r];
      }
    }
    __syncthreads();
    if (khalf == 0) {
      #pragma unroll
      for (int r = 0; r < 16; ++r) {
        int qq = (r & 3) + 8 * (r >> 2) + 4 * lh;
        tile[qhalf * 32 + qq][lr] += A[r];
      }
    }
    __syncthreads();
    if (ob == 0) {
      if (t < 64) {                      // theta
        union { uint4 v4[2]; ushort s[16]; } th;
        #pragma unroll
        for (int c = 0; c < 16; ++c)
          th.s[c] = f2bf(tanhf(tile[t][c] + bias_sh[c]) * L2E);
        uint4* dst = (uint4*)(theta + ((size_t)b * NQ + qt * 64 + t) * 16);
        dst[0] = th.v4[0]; dst[1] = th.v4[1];
      } else if (t < 128) {              // phi
        int idx = t - 64;
        int m = idx >> 2, c4 = (idx & 3) * 4;
        int h2 = m * 2;
        union { uint2 v2; ushort s[4]; } ph;
        #pragma unroll
        for (int cc = 0; cc < 4; ++cc) {
          int c = 16 + c4 + cc;
          float z = fmaxf(fmaxf(tile[h2][c], tile[h2 + 1][c]),
                          fmaxf(tile[32 + h2][c], tile[32 + h2 + 1][c]));
          ph.s[cc] = f2bf(tanhf(z + bias_sh[c]));
        }
        *(uint2*)(phi + ((size_t)b * NM + qt * 16 + m) * 16 + c4) = ph.v2;
      }
    } else {                             // g -> pooled f32 staging (both halves)
      if (t < 128) {
        int cb = (ob - 1) * 32;
        int m = t >> 3, c4 = (t & 7) * 4;
        int h2 = m * 2;
        #pragma unroll
        for (int cc = 0; cc < 4; ++cc) {
          int c = c4 + cc;
          float z = fmaxf(fmaxf(tile[h2][c], tile[h2 + 1][c]),
                          fmaxf(tile[32 + h2][c], tile[32 + h2 + 1][c]));
          gpool[m][cb + c] = z + bias_sh[32 + cb + c];
        }
      }
    }
  }
  __syncthreads();

  // frag-pack: gFu[((b*256+qt)*2+ct)*64+lane], j-th bf16 = pooled[(lane>>5)*8+j][ct*32+(lane&31)]
  if (t < 128) {
    int ct = t >> 6, lane = t & 63;
    int rbase = (lane >> 5) * 8;
    int col = ct * 32 + (lane & 31);
    union { uint4 v4; ushort s[8]; } o;
    #pragma unroll
    for (int j = 0; j < 8; ++j) o.s[j] = f2bf(gpool[rbase + j][col]);
    gFu[(((size_t)b * 256 + qt) * 2 + ct) * 64 + lane] = o.v4;
  }
}

// ---------------- denominator + scale (frag-direct) ----------------
// Grid 256 flat, batch-XCD swizzle: xcd = idx&7 -> b = xcd>>2,
// mb = (xcd&3)*32 + (idx>>3). Each XCD serves ONE batch's theta stream.
// Post-loop: read gFu frags, scale per-m by dinv, write gsF (no transpose).
__global__ __launch_bounds__(1024, 2) void k_denom2(
    const ushort* __restrict__ theta, const ushort* __restrict__ phi,
    const uint4* __restrict__ gFu, uint4* __restrict__ gsF)
{
  int idx = blockIdx.x;              // 0..255
  int xcd = idx & 7;
  int b = xcd >> 2;
  int mb = (xcd & 3) * 32 + (idx >> 3);   // 0..127
  int t = threadIdx.x;
  int w = t >> 6, l = t & 63, lr = l & 31, lh = l >> 5;
  int mbase = mb * 32;

  __shared__ float part[16][33];
  __shared__ float dinv_sh[32];

  bf16x8 pB = __builtin_bit_cast(bf16x8, *(const uint4*)(phi + ((size_t)b * NM + mbase + lr) * 16 + lh * 8));
  const ushort* thb = theta + ((size_t)b * NQ + w * 1024 + lr) * 16 + lh * 8;

  bf16x8 tA1 = __builtin_bit_cast(bf16x8, *(const uint4*)(thb + 512));
  f32x16 S;
  #pragma unroll
  for (int i = 0; i < 16; ++i) S[i] = 0.f;
  S = mfma_bf16(__builtin_bit_cast(bf16x8, *(const uint4*)thb), pB, S);

  float s = 0.f;
  for (int it = 0; it < 32; ++it) {
    bf16x8 tA2 = __builtin_bit_cast(bf16x8, *(const uint4*)(thb + (size_t)((it + 2) & 31) * 512));
    __builtin_amdgcn_sched_barrier(0);
    f32x16 Sn;
    #pragma unroll
    for (int i = 0; i < 16; ++i) Sn[i] = 0.f;
    Sn = mfma_bf16(tA1, pB, Sn);          // next tile's S overlaps this exp block
    #pragma unroll
    for (int r = 0; r < 16; ++r) s += fexp2(S[r]);
    S = Sn; tA1 = tA2;
  }
  s += __shfl_xor(s, 32, 64);
  if (l < 32) part[w][lr] = s;
  __syncthreads();

  if (t < 32) {
    float d = 0.f;
    #pragma unroll
    for (int p = 0; p < 16; ++p) d += part[p][t];
    dinv_sh[t] = 1.f / d;
  }
  __syncthreads();

  if (t < 256) {
    int ms_loc = t >> 7, ct = (t >> 6) & 1, lane = t & 63;
    size_t fi = (((size_t)b * 256 + (mbase >> 4) + ms_loc) * 2 + ct) * 64 + lane;
    union { uint4 v4; ushort s[8]; } v;
    v.v4 = gFu[fi];
    int mloc0 = ms_loc * 16 + (lane >> 5) * 8;
    #pragma unroll
    for (int j = 0; j < 8; ++j) v.s[j] = f2bf(bf2f(v.s[j]) * dinv_sh[mloc0 + j]);
    gsF[fi] = v.v4;
  }
}

// ---------------- fused attention + output (R20 champion, unchanged) ----------
__global__ __launch_bounds__(256, 3) void k_attn(
    const ushort* __restrict__ theta, const ushort* __restrict__ phi,
    const uint4* __restrict__ gsF, const uint4* __restrict__ wF,
    const float* __restrict__ bagg, const void* __restrict__ x,
    const void* __restrict__ gamma, void* __restrict__ out_base)
{
  int idx = blockIdx.x;              // 0..511
  int xcd = idx & 7, slot = idx >> 3;
  int b = xcd >> 2;
  int q0 = ((xcd & 3) * 64 + slot) * 64;
  int t = threadIdx.x;
  int mq = t >> 6, l = t & 63, lr = l & 31, lh = l >> 5;

  __shared__ int cnt_sh[2];
  __shared__ float agPart[4][32][65];
  __shared__ __align__(16) ushort agF[32][80];

  int f = sniff_block(x, t, cnt_sh);

  bf16x8 tB0 = __builtin_bit_cast(bf16x8, *(const uint4*)(theta + ((size_t)b * NQ + q0 + lr) * 16 + lh * 8));
  bf16x8 tB1 = __builtin_bit_cast(bf16x8, *(const uint4*)(theta + ((size_t)b * NQ + q0 + 32 + lr) * 16 + lh * 8));

  const ushort* phb = phi + ((size_t)b * NM + lr) * 16 + lh * 8;
  const uint4* gF = gsF + (size_t)b * 32768;

  f32x16 a00, a01, a10, a11;
  #pragma unroll
  for (int i = 0; i < 16; ++i) { a00[i] = 0.f; a01[i] = 0.f; a10[i] = 0.f; a11[i] = 0.f; }
  f32x16 zero16;
  #pragma unroll
  for (int i = 0; i < 16; ++i) zero16[i] = 0.f;

  size_t gb0 = (size_t)(mq * 2) * 128;
  uint4 g00 = gF[gb0 + l];
  uint4 g01 = gF[gb0 + 64 + l];
  uint4 g10 = gF[gb0 + 128 + l];
  uint4 g11 = gF[gb0 + 192 + l];
  bf16x8 pA = __builtin_bit_cast(bf16x8, *(const uint4*)(phb + (size_t)(mq * 32) * 16));

  for (int it = 0; it < 32; ++it) {
    int it1 = (it + 1) & 31;
    size_t gb = (size_t)(mq * 2 + it1 * 8) * 128;
    uint4 n00 = gF[gb + l];
    uint4 n01 = gF[gb + 64 + l];
    uint4 n10 = gF[gb + 128 + l];
    uint4 n11 = gF[gb + 192 + l];
    bf16x8 pAn = __builtin_bit_cast(bf16x8, *(const uint4*)(phb + (size_t)(mq * 32 + it1 * 128) * 16));
    __builtin_amdgcn_sched_barrier(0);

    f32x16 Sa = mfma_bf16(pA, tB0, zero16);
    f32x16 Sb = mfma_bf16(pA, tB1, zero16);

    uint u0, u1, u2, u3, u4, u5, u6, u7;

    #pragma unroll
    for (int r = 0; r < 16; ++r) Sa[r] = fexp2(Sa[r]);
    asm("v_cvt_pk_bf16_f32 %0, %1, %2" : "=v"(u0) : "v"(Sa[0]),  "v"(Sa[1]));
    asm("v_cvt_pk_bf16_f32 %0, %1, %2" : "=v"(u1) : "v"(Sa[2]),  "v"(Sa[3]));
    asm("v_cvt_pk_bf16_f32 %0, %1, %2" : "=v"(u2) : "v"(Sa[4]),  "v"(Sa[5]));
    asm("v_cvt_pk_bf16_f32 %0, %1, %2" : "=v"(u3) : "v"(Sa[6]),  "v"(Sa[7]));
    asm("v_cvt_pk_bf16_f32 %0, %1, %2" : "=v"(u4) : "v"(Sa[8]),  "v"(Sa[9]));
    asm("v_cvt_pk_bf16_f32 %0, %1, %2" : "=v"(u5) : "v"(Sa[10]), "v"(Sa[11]));
    asm("v_cvt_pk_bf16_f32 %0, %1, %2" : "=v"(u6) : "v"(Sa[12]), "v"(Sa[13]));
    asm("v_cvt_pk_bf16_f32 %0, %1, %2" : "=v"(u7) : "v"(Sa[14]), "v"(Sa[15]));
    asm("v_permlane32_swap_b32 %0, %1" : "+v"(u0), "+v"(u2));
    asm("v_permlane32_swap_b32 %0, %1" : "+v"(u1), "+v"(u3));
    asm("v_permlane32_swap_b32 %0, %1" : "+v"(u4), "+v"(u6));
    asm("v_permlane32_swap_b32 %0, %1" : "+v"(u5), "+v"(u7));
    {
      uint4 fa0 = make_uint4(u0, u1, u2, u3);
      uint4 fa1 = make_uint4(u4, u5, u6, u7);
      a00 = mfma_bf16(__builtin_bit_cast(bf16x8, fa0), __builtin_bit_cast(bf16x8, g00), a00);
      a01 = mfma_bf16(__builtin_bit_cast(bf16x8, fa0), __builtin_bit_cast(bf16x8, g01), a01);
      a00 = mfma_bf16(__builtin_bit_cast(bf16x8, fa1), __builtin_bit_cast(bf16x8, g10), a00);
      a01 = mfma_bf16(__builtin_bit_cast(bf16x8, fa1), __builtin_bit_cast(bf16x8, g11), a01);
    }

    #pragma unroll
    for (int r = 0; r < 16; ++r) Sb[r] = fexp2(Sb[r]);
    asm("v_cvt_pk_bf16_f32 %0, %1, %2" : "=v"(u0) : "v"(Sb[0]),  "v"(Sb[1]));
    asm("v_cvt_pk_bf16_f32 %0, %1, %2" : "=v"(u1) : "v"(Sb[2]),  "v"(Sb[3]));
    asm("v_cvt_pk_bf16_f32 %0, %1, %2" : "=v"(u2) : "v"(Sb[4]),  "v"(Sb[5]));
    asm("v_cvt_pk_bf16_f32 %0, %1, %2" : "=v"(u3) : "v"(Sb[6]),  "v"(Sb[7]));
    asm("v_cvt_pk_bf16_f32 %0, %1, %2" : "=v"(u4) : "v"(Sb[8]),  "v"(Sb[9]));
    asm("v_cvt_pk_bf16_f32 %0, %1, %2" : "=v"(u5) : "v"(Sb[10]), "v"(Sb[11]));
    asm("v_cvt_pk_bf16_f32 %0, %1, %2" : "=v"(u6) : "v"(Sb[12]), "v"(Sb[13]));
    asm("v_cvt_pk_bf16_f32 %0, %1, %2" : "=v"(u7) : "v"(Sb[14]), "v"(Sb[15]));
    asm("v_permlane32_swap_b32 %0, %1" : "+v"(u0), "+v"(u2));
    asm("v_permlane32_swap_b32 %0, %1" : "+v"(u1), "+v"(u3));
    asm("v_permlane32_swap_b32 %0, %1" : "+v"(u4), "+v"(u6));
    asm("v_permlane32_swap_b32 %0, %1" : "+v"(u5), "+v"(u7));
    {
      uint4 fb0 = make_uint4(u0, u1, u2, u3);
      uint4 fb1 = make_uint4(u4, u5, u6, u7);
      a10 = mfma_bf16(__builtin_bit_cast(bf16x8, fb0), __builtin_bit_cast(bf16x8, g00), a10);
      a11 = mfma_bf16(__builtin_bit_cast(bf16x8, fb0), __builtin_bit_cast(bf16x8, g01), a11);
      a10 = mfma_bf16(__builtin_bit_cast(bf16x8, fb1), __builtin_bit_cast(bf16x8, g10), a10);
      a11 = mfma_bf16(__builtin_bit_cast(bf16x8, fb1), __builtin_bit_cast(bf16x8, g11), a11);
    }

    pA = pAn;
    g00 = n00; g01 = n01; g10 = n10; g11 = n11;
  }

  float ga = ldany(gamma, 0, f);
  float alpha = 1.f / (1.f + __expf(-ga));

  #pragma unroll
  for (int h = 0; h < 2; ++h) {
    __syncthreads();
    {
      f32x16 ac0 = (h == 0) ? a00 : a10;
      f32x16 ac1 = (h == 0) ? a01 : a11;
      #pragma unroll
      for (int r = 0; r < 16; ++r) {
        int qq = (r & 3) + 8 * (r >> 2) + 4 * lh;
        agPart[mq][qq][lr]      = ac0[r];
        agPart[mq][qq][32 + lr] = ac1[r];
      }
    }
    __syncthreads();
    {
      #pragma unroll
      for (int jj = 0; jj < 8; ++jj) {
        int c = mq * 16 + lh * 8 + jj;
        float vsum = agPart[0][lr][c] + agPart[1][lr][c] + agPart[2][lr][c] + agPart[3][lr][c];
        agF[lr][c] = f2bf(vsum);
      }
    }
    __syncthreads();
    {
      f32x16 oacc;
      #pragma unroll
      for (int i = 0; i < 16; ++i) oacc[i] = 0.f;
      #pragma unroll
      for (int ks = 0; ks < 4; ++ks) {
        bf16x8 aw = __builtin_bit_cast(bf16x8, wF[(mq * 4 + ks) * 64 + l]);
        bf16x8 bg = __builtin_bit_cast(bf16x8, *(const uint4*)&agF[lr][ks * 16 + lh * 8]);
        oacc = mfma_bf16(aw, bg, oacc);
      }
      if (f) {
        float* o0 = (float*)out_base;
        float* o1 = o0 + NX;
        const float* xf = (const float*)x;
        #pragma unroll
        for (int r = 0; r < 16; ++r) {
          int o = mq * 32 + (r & 3) + 8 * (r >> 2) + 4 * lh;
          size_t oi = ((size_t)b * CH + o) * NQ + q0 + h * 32 + lr;
          float ag = oacc[r] + bagg[o];
          o0[oi] = (1.f - alpha) * xf[oi] + alpha * ag;
          o1[oi] = ag;
        }
      } else {
        ushort* o0 = (ushort*)out_base;
        ushort* o1 = o0 + NX;
        const ushort* xu = (const ushort*)x;
        #pragma unroll
        for (int r = 0; r < 16; ++r) {
          int o = mq * 32 + (r & 3) + 8 * (r >> 2) + 4 * lh;
          size_t oi = ((size_t)b * CH + o) * NQ + q0 + h * 32 + lr;
          float ag = oacc[r] + bagg[o];
          o0[oi] = f2bf((1.f - alpha) * bf2f(xu[oi]) + alpha * ag);
          o1[oi] = f2bf(ag);
        }
      }
    }
  }
}

extern "C" void kernel_launch(void* const* d_in, const int* in_sizes, int n_in,
                              void* d_out, int out_size, void* d_ws, size_t ws_size,
                              hipStream_t stream) {
  const void* x    = d_in[0];
  const void* wT   = d_in[1];
  const void* bT   = d_in[2];
  const void* wP   = d_in[3];
  const void* bP   = d_in[4];
  const void* wG   = d_in[5];
  const void* bG   = d_in[6];
  const void* wAG  = d_in[7];
  const void* bAG  = d_in[8];
  const void* gmm  = d_in[9];

  char* ws = (char*)d_ws;
  ushort* theta  = (ushort*)(ws + 0);          // 1 MB
  ushort* phi    = (ushort*)(ws + 1048576);    // 256 KB
  uint4*  gFu    = (uint4*) (ws + 1310720);    // 1 MB unscaled PV B-frags
  uint4*  gsF    = (uint4*) (ws + 3407872);    // 1 MB scaled PV B-frags
  uint4*  wFg    = (uint4*) (ws + 4456448);    // 16 KB epilogue A-frags
  float*  bagg   = (float*) (ws + 4472832);    // 512 B bAG biases

  k_proj<<<dim3(256, 2), dim3(256), 0, stream>>>(x, wT, bT, wP, bP, wG, bG, wAG, bAG,
                                                 theta, phi, gFu, wFg, bagg);
  k_denom2<<<dim3(256), dim3(1024), 0, stream>>>(theta, phi, gFu, gsF);
  k_attn<<<dim3(512), dim3(256), 0, stream>>>(theta, phi, gsF, wFg, bagg, x, gmm, d_out);
}